// Round 1
// baseline (908.774 us; speedup 1.0000x reference)
//
#include <hip/hip_runtime.h>
#include <stdint.h>

#define DEV static __device__ __forceinline__

typedef unsigned short u16;
typedef unsigned int u32;
typedef __attribute__((ext_vector_type(4))) float f32x4;
typedef __attribute__((ext_vector_type(8))) short bf16x8;

DEV float bf2f(u16 u) { u32 x = ((u32)u) << 16; float f; __builtin_memcpy(&f, &x, 4); return f; }
DEV u16 f2bf(float f) { u32 x; __builtin_memcpy(&x, &f, 4); x = x + 0x7fffu + ((x >> 16) & 1u); return (u16)(x >> 16); }
DEV float lo16(u32 p) { u32 x = p << 16; float f; __builtin_memcpy(&f, &x, 4); return f; }
DEV float hi16(u32 p) { u32 x = p & 0xffff0000u; float f; __builtin_memcpy(&f, &x, 4); return f; }
DEV u32 pack2(float a, float b) { return (u32)f2bf(a) | ((u32)f2bf(b) << 16); }

DEV f32x4 mfma16(bf16x8 a, bf16x8 b, f32x4 c) {
  return __builtin_amdgcn_mfma_f32_16x16x32_bf16(a, b, c, 0, 0, 0);
}

DEV void gl_lds16(const u16* g, u16* l) {
  __builtin_amdgcn_global_load_lds((const __attribute__((address_space(1))) void*)g,
                                   (__attribute__((address_space(3))) void*)l, 16, 0, 0);
}

// ---------------- weight prep ----------------
// Wq_eff = Wq[g=0] + Wq[g=1] (group-sum folded into projection), cast bf16
__global__ __launch_bounds__(256) void prep_wqe_kernel(const float* __restrict__ Wq, u16* __restrict__ out) {
  int id = blockIdx.x * 256 + threadIdx.x;           // 262144 float4 units
  float4 a = ((const float4*)Wq)[id];
  float4 b = ((const float4*)Wq)[id + 262144];       // +1024*1024 floats
  ushort4 o; o.x = f2bf(a.x + b.x); o.y = f2bf(a.y + b.y); o.z = f2bf(a.z + b.z); o.w = f2bf(a.w + b.w);
  ((ushort4*)out)[id] = o;
}

__global__ __launch_bounds__(256) void cast_w_kernel(const float* __restrict__ src, u16* __restrict__ dst) {
  int id = blockIdx.x * 256 + threadIdx.x;
  float4 a = ((const float4*)src)[id];
  ushort4 o; o.x = f2bf(a.x); o.y = f2bf(a.y); o.z = f2bf(a.z); o.w = f2bf(a.w);
  ((ushort4*)dst)[id] = o;
}

// Wkc [64][16384] f32 -> WT [16384][64] bf16 (coalesced inner-o reads in compression)
__global__ __launch_bounds__(256) void transpose_wc_kernel(const float* __restrict__ W, u16* __restrict__ WT) {
  int id = blockIdx.x * 256 + threadIdx.x;           // 1048576
  int j = id >> 6, o = id & 63;
  WT[id] = f2bf(W[(size_t)o * 16384 + j]);
}

__global__ __launch_bounds__(256) void rope_table_kernel(float* __restrict__ ct, float* __restrict__ st) {
  int id = blockIdx.x * 256 + threadIdx.x;           // 2048*32
  int t = id >> 5, i = id & 31;
  double ang = (double)t * pow(10000.0, -(double)(2 * i) / 64.0);
  ct[id] = (float)cos(ang);
  st[id] = (float)sin(ang);
}

// ---------------- layernorm (one block per 1024-row) ----------------
__global__ __launch_bounds__(256) void ln_kernel(const float* __restrict__ x, const float* __restrict__ w,
                                                 const float* __restrict__ b, u16* __restrict__ out) {
  int row = blockIdx.x, t = threadIdx.x;
  float4 v = ((const float4*)(x + (size_t)row * 1024))[t];
  float s = v.x + v.y + v.z + v.w;
  float s2 = v.x * v.x + v.y * v.y + v.z * v.z + v.w * v.w;
#pragma unroll
  for (int off = 32; off; off >>= 1) { s += __shfl_xor(s, off, 64); s2 += __shfl_xor(s2, off, 64); }
  __shared__ float red[8];
  if ((t & 63) == 0) { red[t >> 6] = s; red[4 + (t >> 6)] = s2; }
  __syncthreads();
  s = red[0] + red[1] + red[2] + red[3];
  s2 = red[4] + red[5] + red[6] + red[7];
  float mu = s * 0.0009765625f;
  float var = s2 * 0.0009765625f - mu * mu;
  float rstd = rsqrtf(var + 1e-5f);
  float4 wv = ((const float4*)w)[t];
  float4 bv = ((const float4*)b)[t];
  ushort4 o;
  o.x = f2bf((v.x - mu) * rstd * wv.x + bv.x);
  o.y = f2bf((v.y - mu) * rstd * wv.y + bv.y);
  o.z = f2bf((v.z - mu) * rstd * wv.z + bv.z);
  o.w = f2bf((v.w - mu) * rstd * wv.w + bv.w);
  *(ushort4*)(out + (size_t)row * 1024 + t * 4) = o;
}

// ---------------- NT GEMM: C[m][n] = sum_k A[m*K+k]*B[n*K+k]  (m97-style 128x128, BK=32) ----------------
template <int OUTF32>
__global__ __launch_bounds__(256, 2) void gemm_nt(const u16* __restrict__ A, const u16* __restrict__ B,
                                                  void* __restrict__ Cout, int M, int Nd, int K) {
  __shared__ u16 As[4096], Bs[4096];                 // [128 rows][32 k] each, quarter-XOR-swizzled
  int tid = threadIdx.x, lane = tid & 63, wv = tid >> 6;
  int l15 = lane & 15, lq = lane >> 4;
  int bm = blockIdx.y * 128, bn = blockIdx.x * 128;
  int wm = (wv >> 1) * 64, wn = (wv & 1) * 64;
  f32x4 acc[4][4] = {};
  for (int k0 = 0; k0 < K; k0 += 32) {
    __syncthreads();                                 // previous iter's LDS reads done
#pragma unroll
    for (int it = 0; it < 2; ++it) {
      int ia = wv * 2 + it;                          // 8 1KB slabs per tile
      int row = ia * 16 + (lane >> 2);
      int qs = lane & 3;
      int qg = qs ^ (row & 3);                       // pre-swizzled global quarter
      gl_lds16(A + (size_t)(bm + row) * K + k0 + qg * 8, &As[ia * 512]);
      gl_lds16(B + (size_t)(bn + row) * K + k0 + qg * 8, &Bs[ia * 512]);
    }
    __syncthreads();                                 // vmcnt(0) drain before use
    bf16x8 af[4], bfr[4];
#pragma unroll
    for (int mt = 0; mt < 4; ++mt) {
      int r = wm + mt * 16 + l15;
      af[mt] = *(const bf16x8*)&As[r * 32 + ((lq ^ (r & 3)) * 8)];
    }
#pragma unroll
    for (int nt = 0; nt < 4; ++nt) {
      int r = wn + nt * 16 + l15;
      bfr[nt] = *(const bf16x8*)&Bs[r * 32 + ((lq ^ (r & 3)) * 8)];
    }
#pragma unroll
    for (int mt = 0; mt < 4; ++mt)
#pragma unroll
      for (int nt = 0; nt < 4; ++nt)
        acc[mt][nt] = mfma16(af[mt], bfr[nt], acc[mt][nt]);
  }
#pragma unroll
  for (int mt = 0; mt < 4; ++mt)
#pragma unroll
    for (int nt = 0; nt < 4; ++nt)
#pragma unroll
      for (int i = 0; i < 4; ++i) {
        int row = bm + wm + mt * 16 + lq * 4 + i;
        int col = bn + wn + nt * 16 + l15;
        if (OUTF32) ((float*)Cout)[(size_t)row * Nd + col] = acc[mt][nt][i];
        else ((u16*)Cout)[(size_t)row * Nd + col] = f2bf(acc[mt][nt][i]);
      }
}

// ---------------- RoPE in place on qc and kh ([16384][1024] bf16, 64-col heads, interleaved pairs) -------
__global__ __launch_bounds__(256) void rope_kernel(u16* __restrict__ qc, u16* __restrict__ kh,
                                                   const float* __restrict__ ct, const float* __restrict__ st) {
  u32 id = blockIdx.x * 256 + threadIdx.x;
  u16* base = qc;
  if (id >= 2097152u) { base = kh; id -= 2097152u; }
  size_t e0 = (size_t)id * 8;
  int row = (int)(e0 >> 10);
  int col = (int)(e0 & 1023);
  int t = row & 2047;
  int i0 = (col & 63) >> 1;                          // multiple of 4
  float4 c = *(const float4*)(ct + t * 32 + i0);
  float4 s = *(const float4*)(st + t * 32 + i0);
  uint4 u = *(const uint4*)(base + e0);
  float x0 = lo16(u.x), x1 = hi16(u.x), x2 = lo16(u.y), x3 = hi16(u.y);
  float x4 = lo16(u.z), x5 = hi16(u.z), x6 = lo16(u.w), x7 = hi16(u.w);
  uint4 o;
  o.x = pack2(x0 * c.x - x1 * s.x, x1 * c.x + x0 * s.x);
  o.y = pack2(x2 * c.y - x3 * s.y, x3 * c.y + x2 * s.y);
  o.z = pack2(x4 * c.z - x5 * s.z, x5 * c.z + x4 * s.z);
  o.w = pack2(x6 * c.w - x7 * s.w, x7 * c.w + x6 * s.w);
  *(uint4*)(base + e0) = o;
}

// ---------------- segment compression: 64 outputs = elu(x[16384] @ W^T + b) per (n,h,s,kv) --------------
// block: (n,h, segment-pair, kv). wave w covers j quarter; lane o = output. W transposed -> coalesced.
__global__ __launch_bounds__(256) void compress_kernel(const u16* __restrict__ kh, const u16* __restrict__ vh,
                                                       const u16* __restrict__ wkct, const u16* __restrict__ wvct,
                                                       const float* __restrict__ bkc, const float* __restrict__ bvc,
                                                       u16* __restrict__ kp, u16* __restrict__ vtp) {
  int bid = blockIdx.x;                              // 768
  int kv = bid & 1, rid = bid >> 1;                  // 384 = 8n*16h*3sp
  int n = rid / 48, rem = rid % 48, h = rem / 3, sp = rem % 3;
  const u16* src = kv ? vh : kh;
  const u16* WT = kv ? wvct : wkct;
  int t = threadIdx.x;
  int w = __builtin_amdgcn_readfirstlane(t >> 6);
  int o = t & 63;
  const u16* s0 = src + ((size_t)(n * 2048 + (sp * 2 + 0) * 256)) * 1024 + h * 64;
  const u16* s1 = src + ((size_t)(n * 2048 + (sp * 2 + 1) * 256)) * 1024 + h * 64;
  const u16* wp = WT + o;
  float a0 = 0.f, a1 = 0.f;
  for (int j2 = 0; j2 < 2048; ++j2) {
    int j = w * 4096 + 2 * j2;                       // x[j] pairs: j = tau*64 + d
    int tau = j >> 6, d = j & 63;
    u32 p0 = *(const u32*)(s0 + (size_t)tau * 1024 + d);   // wave-uniform broadcast
    u32 p1 = *(const u32*)(s1 + (size_t)tau * 1024 + d);
    float w0 = bf2f(wp[(size_t)j * 64]);
    float w1 = bf2f(wp[(size_t)j * 64 + 64]);
    a0 += lo16(p0) * w0 + hi16(p0) * w1;
    a1 += lo16(p1) * w0 + hi16(p1) * w1;
  }
  __shared__ float red[2][4][64];
  red[0][w][o] = a0; red[1][w][o] = a1;
  __syncthreads();
  if (t < 128) {
    int seg = t >> 6, oo = t & 63;
    float v = red[seg][0][oo] + red[seg][1][oo] + red[seg][2][oo] + red[seg][3][oo] + (kv ? bvc[oo] : bkc[oo]);
    v = v > 0.f ? v : expm1f(v);                     // elu
    int s = sp * 2 + seg;
    if (kv) vtp[((size_t)(n * 16 + h) * 64 + oo) * 576 + s] = f2bf(v);
    else    kp[((size_t)(n * 16 + h) * 576 + s) * 64 + oo] = f2bf(v);
  }
}

// ---------------- copy recent 512 rows into packed K [nh][576][64] and V^T [nh][64][576]; zero pad ------
__global__ __launch_bounds__(256) void copy_recent_kernel(const u16* __restrict__ kh, const u16* __restrict__ vh,
                                                          u16* __restrict__ kp, u16* __restrict__ vtp) {
  int bid = blockIdx.x;
  if (bid < 2280) {                                  // K rows T=6..575
    int u = bid * 256 + threadIdx.x;                 // = (nh*570 + (T-6))*8 + dq8
    int dq8 = u & 7; int rest = u >> 3; int Tm6 = rest % 570; int nh = rest / 570;
    if (nh >= 128) return;
    uint4 val = {0, 0, 0, 0};
    if (Tm6 < 512) {
      int n = nh >> 4, h = nh & 15;
      val = *(const uint4*)&kh[((size_t)(n * 2048 + 1536 + Tm6)) * 1024 + h * 64 + dq8 * 8];
    }
    *(uint4*)&kp[((size_t)nh * 576 + 6 + Tm6) * 64 + dq8 * 8] = val;
  } else {                                           // V^T cols
    int u = (bid - 2280) * 256 + threadIdx.x;        // = (nh*72 + tch)*64 + d
    int d = u & 63; int rest = u >> 6; int tch = rest % 72; int nh = rest / 72;
    if (nh >= 128) return;
    int n = nh >> 4, h = nh & 15;
#pragma unroll
    for (int ii = 0; ii < 8; ++ii) {
      int T = tch * 8 + ii;
      if (T < 6) continue;                           // written by compression
      u16 v = 0;
      if (T < 518) v = vh[((size_t)(n * 2048 + 1536 + (T - 6))) * 1024 + h * 64 + d];
      vtp[((size_t)nh * 64 + d) * 576 + T] = v;
    }
  }
}

// ---------------- fused attention: per (n,h,64 q-rows); flash over 9 chunks of 64 T ---------------------
__global__ __launch_bounds__(256) void attn_kernel(const u16* __restrict__ qc, const u16* __restrict__ Kp,
                                                   const u16* __restrict__ VTp, u16* __restrict__ ao) {
  const float LOG2E = 1.4426950408889634f;
  int qt = blockIdx.x, h = blockIdx.y, n = blockIdx.z;
  int tid = threadIdx.x, lane = tid & 63, wv = tid >> 6;
  int l15 = lane & 15, lq = lane >> 4;
  __shared__ u16 KS[4096], VS[4096];                 // 64x64 bf16 chunks, row-XOR-swizzled
  __shared__ u16 PS[4][2048];                        // per-wave P [16][64]
  int q0 = qt * 64 + wv * 16;
  const u16* qrowp = qc + ((size_t)(n * 2048 + q0 + l15)) * 1024 + h * 64;
  bf16x8 aq0 = *(const bf16x8*)(qrowp + lq * 8);
  bf16x8 aq1 = *(const bf16x8*)(qrowp + 32 + lq * 8);
  const u16* Kph = Kp + (size_t)(n * 16 + h) * 576 * 64;
  const u16* Vph = VTp + (size_t)(n * 16 + h) * 64 * 576;
  f32x4 oa[4] = {};
  float mi[4] = {-3e38f, -3e38f, -3e38f, -3e38f};
  float li[4] = {0.f, 0.f, 0.f, 0.f};
  u16* PSW = &PS[wv][0];
  for (int tc = 0; tc < 9; ++tc) {
    int Tbase = tc * 64;
    __syncthreads();
#pragma unroll
    for (int it = 0; it < 2; ++it) {                 // stage K,V chunk (8KB each)
      int slot = it * 256 + tid;                     // 0..511 16B slots
      int row = slot >> 3, qq = slot & 7;
      int sw = (qq ^ (row & 7)) * 8;
      *(uint4*)&KS[row * 64 + sw] = *(const uint4*)&Kph[(size_t)(Tbase + row) * 64 + qq * 8];
      *(uint4*)&VS[row * 64 + sw] = *(const uint4*)&Vph[(size_t)row * 576 + Tbase + qq * 8];
    }
    __syncthreads();
    // S = Q @ K^T for 16 q-rows x 64 T
    f32x4 sv[4];
#pragma unroll
    for (int tt = 0; tt < 4; ++tt) {
      int row = tt * 16 + l15, r7 = row & 7;
      bf16x8 b0 = *(const bf16x8*)&KS[row * 64 + ((lq ^ r7) * 8)];
      bf16x8 b1 = *(const bf16x8*)&KS[row * 64 + (((4 | lq) ^ r7) * 8)];
      f32x4 c = {0.f, 0.f, 0.f, 0.f};
      c = mfma16(aq0, b0, c);
      c = mfma16(aq1, b1, c);
      sv[tt] = c;
    }
    // logits: 30*tanh(s/(8*30)); mask T<=t && T<518; online softmax
    float p[4][4];
    float mc[4] = {-3e38f, -3e38f, -3e38f, -3e38f};
    int qb = q0 + lq * 4;
#pragma unroll
    for (int tt = 0; tt < 4; ++tt) {
      int T = Tbase + tt * 16 + l15;
      bool tval = (T < 518);
#pragma unroll
      for (int i = 0; i < 4; ++i) {
        float vr = sv[tt][i] * 0.125f;
        float e = exp2f(vr * 0.09617966939259757f);  // exp(2*(vr/30))
        float t30 = 30.f - 60.f / (e + 1.f);         // 30*tanh(vr/30)
        bool ok = tval && (T <= qb + i);
        float sval = ok ? t30 : -3.0e38f;
        p[tt][i] = sval;
        mc[i] = fmaxf(mc[i], sval);
      }
    }
#pragma unroll
    for (int i = 0; i < 4; ++i)
#pragma unroll
      for (int off = 1; off < 16; off <<= 1) mc[i] = fmaxf(mc[i], __shfl_xor(mc[i], off, 64));
    float rs[4];
#pragma unroll
    for (int i = 0; i < 4; ++i) {
      float mn = fmaxf(mi[i], mc[i]);
      float sc = exp2f((mi[i] - mn) * LOG2E);
      mi[i] = mn; li[i] *= sc; rs[i] = 0.f;
      oa[0][i] *= sc; oa[1][i] *= sc; oa[2][i] *= sc; oa[3][i] *= sc;
#pragma unroll
      for (int tt = 0; tt < 4; ++tt) {
        float pe = exp2f((p[tt][i] - mn) * LOG2E);
        rs[i] += pe; p[tt][i] = pe;
      }
    }
#pragma unroll
    for (int i = 0; i < 4; ++i) {
#pragma unroll
      for (int off = 1; off < 16; off <<= 1) rs[i] += __shfl_xor(rs[i], off, 64);
      li[i] += rs[i];
    }
    // P -> LDS (bf16, swizzled), then PV
#pragma unroll
    for (int tt = 0; tt < 4; ++tt)
#pragma unroll
      for (int i = 0; i < 4; ++i) {
        int prow = lq * 4 + i;
        int cb = (tt * 16 + l15) * 2;
        *(u16*)((char*)PSW + prow * 128 + (cb ^ ((prow & 7) << 4))) = f2bf(p[tt][i]);
      }
    bf16x8 pa0, pa1;
    {
      int prow = l15, r7 = (prow & 7) << 4;
      pa0 = *(const bf16x8*)((char*)PSW + prow * 128 + ((lq * 16) ^ r7));
      pa1 = *(const bf16x8*)((char*)PSW + prow * 128 + (((4 | lq) * 16) ^ r7));
    }
#pragma unroll
    for (int ct = 0; ct < 4; ++ct) {
      int row = ct * 16 + l15, r7 = row & 7;
      bf16x8 bv0 = *(const bf16x8*)&VS[row * 64 + ((lq ^ r7) * 8)];
      bf16x8 bv1 = *(const bf16x8*)&VS[row * 64 + (((4 | lq) ^ r7) * 8)];
      oa[ct] = mfma16(pa0, bv0, oa[ct]);
      oa[ct] = mfma16(pa1, bv1, oa[ct]);
    }
  }
  u16* aop = ao + ((size_t)(n * 2048)) * 1024 + h * 64;
#pragma unroll
  for (int i = 0; i < 4; ++i) {
    float inv = 1.0f / li[i];
    int q = q0 + lq * 4 + i;
#pragma unroll
    for (int ct = 0; ct < 4; ++ct) {
      int dv = ct * 16 + l15;
      aop[(size_t)q * 1024 + dv] = f2bf(oa[ct][i] * inv);
    }
  }
}

extern "C" void kernel_launch(void* const* d_in, const int* in_sizes, int n_in,
                              void* d_out, int out_size, void* d_ws, size_t ws_size,
                              hipStream_t stream) {
  const float* q_in = (const float*)d_in[0];
  const float* k_in = (const float*)d_in[1];
  const float* v_in = (const float*)d_in[2];
  const float* ln_w = (const float*)d_in[3];
  const float* ln_b = (const float*)d_in[4];
  const float* Wq = (const float*)d_in[5];
  const float* Wk = (const float*)d_in[6];
  const float* Wv = (const float*)d_in[7];
  const float* Wo = (const float*)d_in[8];
  const float* Wkc = (const float*)d_in[9];
  const float* bkc = (const float*)d_in[10];
  const float* Wvc = (const float*)d_in[11];
  const float* bvc = (const float*)d_in[12];

  char* ws = (char*)d_ws;
  const size_t MB = 1u << 20;
  u16* wqe = (u16*)(ws + 0 * MB);
  u16* wkb = (u16*)(ws + 2 * MB);
  u16* wvb = (u16*)(ws + 4 * MB);
  u16* wob = (u16*)(ws + 6 * MB);
  u16* wkct = (u16*)(ws + 8 * MB);
  u16* wvct = (u16*)(ws + 10 * MB);
  float* cost = (float*)(ws + 12 * MB);
  float* sint = (float*)(ws + 12 * MB + 262144);
  u16* xn = (u16*)(ws + 13 * MB);    // 32MB, reused per tensor
  u16* qcb = (u16*)(ws + 45 * MB);   // 32MB
  u16* khb = (u16*)(ws + 77 * MB);   // 32MB
  u16* vhb = (u16*)(ws + 109 * MB);  // 32MB
  u16* kp = (u16*)(ws + 141 * MB);   // 9.0MB
  u16* vtp = (u16*)(ws + 141 * MB + 9437184);
  u16* aob = khb;                    // kh dead once attention runs

  // weight prep
  prep_wqe_kernel<<<1024, 256, 0, stream>>>(Wq, wqe);
  cast_w_kernel<<<1024, 256, 0, stream>>>(Wk, wkb);
  cast_w_kernel<<<1024, 256, 0, stream>>>(Wv, wvb);
  cast_w_kernel<<<1024, 256, 0, stream>>>(Wo, wob);
  transpose_wc_kernel<<<4096, 256, 0, stream>>>(Wkc, wkct);
  transpose_wc_kernel<<<4096, 256, 0, stream>>>(Wvc, wvct);
  rope_table_kernel<<<256, 256, 0, stream>>>(cost, sint);

  dim3 gg(8, 128);
  // q: LN -> GEMM(Wq_eff)
  ln_kernel<<<16384, 256, 0, stream>>>(q_in, ln_w, ln_b, xn);
  gemm_nt<0><<<gg, 256, 0, stream>>>(xn, wqe, qcb, 16384, 1024, 1024);
  // k
  ln_kernel<<<16384, 256, 0, stream>>>(k_in, ln_w, ln_b, xn);
  gemm_nt<0><<<gg, 256, 0, stream>>>(xn, wkb, khb, 16384, 1024, 1024);
  // v
  ln_kernel<<<16384, 256, 0, stream>>>(v_in, ln_w, ln_b, xn);
  gemm_nt<0><<<gg, 256, 0, stream>>>(xn, wvb, vhb, 16384, 1024, 1024);

  rope_kernel<<<16384, 256, 0, stream>>>(qcb, khb, cost, sint);
  compress_kernel<<<768, 256, 0, stream>>>(khb, vhb, wkct, wvct, bkc, bvc, kp, vtp);
  copy_recent_kernel<<<4584, 256, 0, stream>>>(khb, vhb, kp, vtp);
  attn_kernel<<<dim3(32, 16, 8), 256, 0, stream>>>(qcb, kp, vtp, aob);
  gemm_nt<1><<<gg, 256, 0, stream>>>(aob, wob, (float*)d_out, 16384, 1024, 1024);
}

// Round 2
// 666.372 us; speedup vs baseline: 1.3638x; 1.3638x over previous
//
#include <hip/hip_runtime.h>
#include <stdint.h>

#define DEV static __device__ __forceinline__

typedef unsigned short u16;
typedef unsigned int u32;
typedef __attribute__((ext_vector_type(4))) float f32x4;
typedef __attribute__((ext_vector_type(8))) short bf16x8;

DEV float bf2f(u16 u) { u32 x = ((u32)u) << 16; float f; __builtin_memcpy(&f, &x, 4); return f; }
DEV u16 f2bf(float f) { u32 x; __builtin_memcpy(&x, &f, 4); x = x + 0x7fffu + ((x >> 16) & 1u); return (u16)(x >> 16); }
DEV float lo16(u32 p) { u32 x = p << 16; float f; __builtin_memcpy(&f, &x, 4); return f; }
DEV float hi16(u32 p) { u32 x = p & 0xffff0000u; float f; __builtin_memcpy(&f, &x, 4); return f; }
DEV u32 pack2(float a, float b) { return (u32)f2bf(a) | ((u32)f2bf(b) << 16); }

DEV f32x4 mfma16(bf16x8 a, bf16x8 b, f32x4 c) {
  return __builtin_amdgcn_mfma_f32_16x16x32_bf16(a, b, c, 0, 0, 0);
}

DEV void gl_lds16(const u16* g, u16* l) {
  __builtin_amdgcn_global_load_lds((const __attribute__((address_space(1))) void*)g,
                                   (__attribute__((address_space(3))) void*)l, 16, 0, 0);
}

// ---------------- weight prep ----------------
// Wq_eff = Wq[g=0] + Wq[g=1] (group-sum folded into projection), cast bf16
__global__ __launch_bounds__(256) void prep_wqe_kernel(const float* __restrict__ Wq, u16* __restrict__ out) {
  int id = blockIdx.x * 256 + threadIdx.x;           // 262144 float4 units
  float4 a = ((const float4*)Wq)[id];
  float4 b = ((const float4*)Wq)[id + 262144];       // +1024*1024 floats
  ushort4 o; o.x = f2bf(a.x + b.x); o.y = f2bf(a.y + b.y); o.z = f2bf(a.z + b.z); o.w = f2bf(a.w + b.w);
  ((ushort4*)out)[id] = o;
}

__global__ __launch_bounds__(256) void cast_w_kernel(const float* __restrict__ src, u16* __restrict__ dst) {
  int id = blockIdx.x * 256 + threadIdx.x;
  float4 a = ((const float4*)src)[id];
  ushort4 o; o.x = f2bf(a.x); o.y = f2bf(a.y); o.z = f2bf(a.z); o.w = f2bf(a.w);
  ((ushort4*)dst)[id] = o;
}

__global__ __launch_bounds__(256) void rope_table_kernel(float* __restrict__ ct, float* __restrict__ st) {
  int id = blockIdx.x * 256 + threadIdx.x;           // 2048*32
  int t = id >> 5, i = id & 31;
  double ang = (double)t * pow(10000.0, -(double)(2 * i) / 64.0);
  ct[id] = (float)cos(ang);
  st[id] = (float)sin(ang);
}

// ---------------- layernorm (one block per 1024-row) ----------------
__global__ __launch_bounds__(256) void ln_kernel(const float* __restrict__ x, const float* __restrict__ w,
                                                 const float* __restrict__ b, u16* __restrict__ out) {
  int row = blockIdx.x, t = threadIdx.x;
  float4 v = ((const float4*)(x + (size_t)row * 1024))[t];
  float s = v.x + v.y + v.z + v.w;
  float s2 = v.x * v.x + v.y * v.y + v.z * v.z + v.w * v.w;
#pragma unroll
  for (int off = 32; off; off >>= 1) { s += __shfl_xor(s, off, 64); s2 += __shfl_xor(s2, off, 64); }
  __shared__ float red[8];
  if ((t & 63) == 0) { red[t >> 6] = s; red[4 + (t >> 6)] = s2; }
  __syncthreads();
  s = red[0] + red[1] + red[2] + red[3];
  s2 = red[4] + red[5] + red[6] + red[7];
  float mu = s * 0.0009765625f;
  float var = s2 * 0.0009765625f - mu * mu;
  float rstd = rsqrtf(var + 1e-5f);
  float4 wv = ((const float4*)w)[t];
  float4 bv = ((const float4*)b)[t];
  ushort4 o;
  o.x = f2bf((v.x - mu) * rstd * wv.x + bv.x);
  o.y = f2bf((v.y - mu) * rstd * wv.y + bv.y);
  o.z = f2bf((v.z - mu) * rstd * wv.z + bv.z);
  o.w = f2bf((v.w - mu) * rstd * wv.w + bv.w);
  *(ushort4*)(out + (size_t)row * 1024 + t * 4) = o;
}

// ---------------- NT GEMM: C[m][n] = sum_k A[m*K+k]*B[n*K+k]  (m97-style 128x128, BK=32) ----------------
template <int OUTF32>
__global__ __launch_bounds__(256, 2) void gemm_nt(const u16* __restrict__ A, const u16* __restrict__ B,
                                                  void* __restrict__ Cout, int M, int Nd, int K) {
  __shared__ u16 As[4096], Bs[4096];                 // [128 rows][32 k] each, quarter-XOR-swizzled
  int tid = threadIdx.x, lane = tid & 63, wv = tid >> 6;
  int l15 = lane & 15, lq = lane >> 4;
  int bm = blockIdx.y * 128, bn = blockIdx.x * 128;
  int wm = (wv >> 1) * 64, wn = (wv & 1) * 64;
  f32x4 acc[4][4] = {};
  for (int k0 = 0; k0 < K; k0 += 32) {
    __syncthreads();                                 // previous iter's LDS reads done
#pragma unroll
    for (int it = 0; it < 2; ++it) {
      int ia = wv * 2 + it;                          // 8 1KB slabs per tile
      int row = ia * 16 + (lane >> 2);
      int qs = lane & 3;
      int qg = qs ^ (row & 3);                       // pre-swizzled global quarter
      gl_lds16(A + (size_t)(bm + row) * K + k0 + qg * 8, &As[ia * 512]);
      gl_lds16(B + (size_t)(bn + row) * K + k0 + qg * 8, &Bs[ia * 512]);
    }
    __syncthreads();                                 // vmcnt(0) drain before use
    bf16x8 af[4], bfr[4];
#pragma unroll
    for (int mt = 0; mt < 4; ++mt) {
      int r = wm + mt * 16 + l15;
      af[mt] = *(const bf16x8*)&As[r * 32 + ((lq ^ (r & 3)) * 8)];
    }
#pragma unroll
    for (int nt = 0; nt < 4; ++nt) {
      int r = wn + nt * 16 + l15;
      bfr[nt] = *(const bf16x8*)&Bs[r * 32 + ((lq ^ (r & 3)) * 8)];
    }
#pragma unroll
    for (int mt = 0; mt < 4; ++mt)
#pragma unroll
      for (int nt = 0; nt < 4; ++nt)
        acc[mt][nt] = mfma16(af[mt], bfr[nt], acc[mt][nt]);
  }
#pragma unroll
  for (int mt = 0; mt < 4; ++mt)
#pragma unroll
    for (int nt = 0; nt < 4; ++nt)
#pragma unroll
      for (int i = 0; i < 4; ++i) {
        int row = bm + wm + mt * 16 + lq * 4 + i;
        int col = bn + wn + nt * 16 + l15;
        if (OUTF32) ((float*)Cout)[(size_t)row * Nd + col] = acc[mt][nt][i];
        else ((u16*)Cout)[(size_t)row * Nd + col] = f2bf(acc[mt][nt][i]);
      }
}

// ---------------- RoPE in place on qc and kh ([16384][1024] bf16, 64-col heads, interleaved pairs) -------
__global__ __launch_bounds__(256) void rope_kernel(u16* __restrict__ qc, u16* __restrict__ kh,
                                                   const float* __restrict__ ct, const float* __restrict__ st) {
  u32 id = blockIdx.x * 256 + threadIdx.x;
  u16* base = qc;
  if (id >= 2097152u) { base = kh; id -= 2097152u; }
  size_t e0 = (size_t)id * 8;
  int row = (int)(e0 >> 10);
  int col = (int)(e0 & 1023);
  int t = row & 2047;
  int i0 = (col & 63) >> 1;                          // multiple of 4
  float4 c = *(const float4*)(ct + t * 32 + i0);
  float4 s = *(const float4*)(st + t * 32 + i0);
  uint4 u = *(const uint4*)(base + e0);
  float x0 = lo16(u.x), x1 = hi16(u.x), x2 = lo16(u.y), x3 = hi16(u.y);
  float x4 = lo16(u.z), x5 = hi16(u.z), x6 = lo16(u.w), x7 = hi16(u.w);
  uint4 o;
  o.x = pack2(x0 * c.x - x1 * s.x, x1 * c.x + x0 * s.x);
  o.y = pack2(x2 * c.y - x3 * s.y, x3 * c.y + x2 * s.y);
  o.z = pack2(x4 * c.z - x5 * s.z, x5 * c.z + x4 * s.z);
  o.w = pack2(x6 * c.w - x7 * s.w, x7 * c.w + x6 * s.w);
  *(uint4*)(base + e0) = o;
}

// ---------------- segment compression as MFMA GEMM ----------------
// out[768][64] = elu(X[768][16384] @ W[64][16384]^T + b), per kv type.
// row r = nh*6 + s -> X row = src[(n*2048 + s*256 + tau)*1024 + h*64 + d], k = tau*64+d.
// grid (48, 2); 512 threads = 8 waves; wave wv owns K slice [wv*2048, wv*2048+2048).
__global__ __launch_bounds__(512) void compress_mfma_kernel(
    const u16* __restrict__ kh, const u16* __restrict__ vh,
    const u16* __restrict__ wkcb, const u16* __restrict__ wvcb,
    const float* __restrict__ bkc, const float* __restrict__ bvc,
    u16* __restrict__ kp, u16* __restrict__ vtp) {
  int mt = blockIdx.x, kv = blockIdx.y;
  const u16* src = kv ? vh : kh;
  const u16* W = kv ? wvcb : wkcb;
  int tid = threadIdx.x, lane = tid & 63, wv = tid >> 6;
  int l15 = lane & 15, lq = lane >> 4;
  int r = mt * 16 + l15;                             // row in [0,768)
  int nh = r / 6, s = r % 6;
  int n = nh >> 4, h = nh & 15;
  const u16* arow = src + ((size_t)(n * 2048 + s * 256)) * 1024 + h * 64;
  f32x4 acc[4] = {};
  int kbase = wv * 2048;
#pragma unroll 4
  for (int ks = 0; ks < 64; ++ks) {
    int k0 = kbase + ks * 32;
    int tau = k0 >> 6, d0 = k0 & 63;
    bf16x8 a = *(const bf16x8*)(arow + (size_t)tau * 1024 + d0 + lq * 8);
#pragma unroll
    for (int nt = 0; nt < 4; ++nt) {
      bf16x8 b = *(const bf16x8*)(W + (size_t)(nt * 16 + l15) * 16384 + k0 + lq * 8);
      acc[nt] = mfma16(a, b, acc[nt]);
    }
  }
  // acc fragment: C[row=lq*4+i][col=l15] for o-tile nt
  __shared__ float red[8][16][64];
#pragma unroll
  for (int nt = 0; nt < 4; ++nt)
#pragma unroll
    for (int i = 0; i < 4; ++i)
      red[wv][lq * 4 + i][nt * 16 + l15] = acc[nt][i];
  __syncthreads();
  // 512 threads finalize 1024 outputs (2 each)
  int row = tid >> 5, o0 = (tid & 31) * 2;
  int rr = mt * 16 + row;
  int nh2 = rr / 6, s2 = rr % 6;
#pragma unroll
  for (int j = 0; j < 2; ++j) {
    int o = o0 + j;
    float v = (kv ? bvc[o] : bkc[o]);
#pragma unroll
    for (int w8 = 0; w8 < 8; ++w8) v += red[w8][row][o];
    v = v > 0.f ? v : expm1f(v);                     // elu
    if (kv) vtp[((size_t)nh2 * 64 + o) * 576 + s2] = f2bf(v);
    else    kp[((size_t)nh2 * 576 + s2) * 64 + o] = f2bf(v);
  }
}

// ---------------- copy recent 512 rows into packed K [nh][576][64] and V^T [nh][64][576]; zero pad ------
__global__ __launch_bounds__(256) void copy_recent_kernel(const u16* __restrict__ kh, const u16* __restrict__ vh,
                                                          u16* __restrict__ kp, u16* __restrict__ vtp) {
  int bid = blockIdx.x;
  if (bid < 2280) {                                  // K rows T=6..575
    int u = bid * 256 + threadIdx.x;                 // = (nh*570 + (T-6))*8 + dq8
    int dq8 = u & 7; int rest = u >> 3; int Tm6 = rest % 570; int nh = rest / 570;
    if (nh >= 128) return;
    uint4 val = {0, 0, 0, 0};
    if (Tm6 < 512) {
      int n = nh >> 4, h = nh & 15;
      val = *(const uint4*)&kh[((size_t)(n * 2048 + 1536 + Tm6)) * 1024 + h * 64 + dq8 * 8];
    }
    *(uint4*)&kp[((size_t)nh * 576 + 6 + Tm6) * 64 + dq8 * 8] = val;
  } else {                                           // V^T cols
    int u = (bid - 2280) * 256 + threadIdx.x;        // = (nh*72 + tch)*64 + d
    int d = u & 63; int rest = u >> 6; int tch = rest % 72; int nh = rest / 72;
    if (nh >= 128) return;
    int n = nh >> 4, h = nh & 15;
#pragma unroll
    for (int ii = 0; ii < 8; ++ii) {
      int T = tch * 8 + ii;
      if (T < 6) continue;                           // written by compression
      u16 v = 0;
      if (T < 518) v = vh[((size_t)(n * 2048 + 1536 + (T - 6))) * 1024 + h * 64 + d];
      vtp[((size_t)nh * 64 + d) * 576 + T] = v;
    }
  }
}

// ---------------- fused attention: per (n,h,64 q-rows); flash over 9 chunks of 64 T ---------------------
__global__ __launch_bounds__(256) void attn_kernel(const u16* __restrict__ qc, const u16* __restrict__ Kp,
                                                   const u16* __restrict__ VTp, u16* __restrict__ ao) {
  const float LOG2E = 1.4426950408889634f;
  int qt = blockIdx.x, h = blockIdx.y, n = blockIdx.z;
  int tid = threadIdx.x, lane = tid & 63, wv = tid >> 6;
  int l15 = lane & 15, lq = lane >> 4;
  __shared__ u16 KS[4096], VS[4096];                 // 64x64 bf16 chunks, row-XOR-swizzled
  __shared__ u16 PS[4][2048];                        // per-wave P [16][64]
  int q0 = qt * 64 + wv * 16;
  const u16* qrowp = qc + ((size_t)(n * 2048 + q0 + l15)) * 1024 + h * 64;
  bf16x8 aq0 = *(const bf16x8*)(qrowp + lq * 8);
  bf16x8 aq1 = *(const bf16x8*)(qrowp + 32 + lq * 8);
  const u16* Kph = Kp + (size_t)(n * 16 + h) * 576 * 64;
  const u16* Vph = VTp + (size_t)(n * 16 + h) * 64 * 576;
  f32x4 oa[4] = {};
  float mi[4] = {-3e38f, -3e38f, -3e38f, -3e38f};
  float li[4] = {0.f, 0.f, 0.f, 0.f};
  u16* PSW = &PS[wv][0];
  for (int tc = 0; tc < 9; ++tc) {
    int Tbase = tc * 64;
    __syncthreads();
#pragma unroll
    for (int it = 0; it < 2; ++it) {                 // stage K,V chunk (8KB each)
      int slot = it * 256 + tid;                     // 0..511 16B slots
      int row = slot >> 3, qq = slot & 7;
      int sw = (qq ^ (row & 7)) * 8;
      *(uint4*)&KS[row * 64 + sw] = *(const uint4*)&Kph[(size_t)(Tbase + row) * 64 + qq * 8];
      *(uint4*)&VS[row * 64 + sw] = *(const uint4*)&Vph[(size_t)row * 576 + Tbase + qq * 8];
    }
    __syncthreads();
    // S = Q @ K^T for 16 q-rows x 64 T
    f32x4 sv[4];
#pragma unroll
    for (int tt = 0; tt < 4; ++tt) {
      int row = tt * 16 + l15, r7 = row & 7;
      bf16x8 b0 = *(const bf16x8*)&KS[row * 64 + ((lq ^ r7) * 8)];
      bf16x8 b1 = *(const bf16x8*)&KS[row * 64 + (((4 | lq) ^ r7) * 8)];
      f32x4 c = {0.f, 0.f, 0.f, 0.f};
      c = mfma16(aq0, b0, c);
      c = mfma16(aq1, b1, c);
      sv[tt] = c;
    }
    // logits: 30*tanh(s/(8*30)); mask T<=t && T<518; online softmax
    float p[4][4];
    float mc[4] = {-3e38f, -3e38f, -3e38f, -3e38f};
    int qb = q0 + lq * 4;
#pragma unroll
    for (int tt = 0; tt < 4; ++tt) {
      int T = Tbase + tt * 16 + l15;
      bool tval = (T < 518);
#pragma unroll
      for (int i = 0; i < 4; ++i) {
        float vr = sv[tt][i] * 0.125f;
        float e = exp2f(vr * 0.09617966939259757f);  // exp(2*(vr/30))
        float t30 = 30.f - 60.f / (e + 1.f);         // 30*tanh(vr/30)
        bool ok = tval && (T <= qb + i);
        float sval = ok ? t30 : -3.0e38f;
        p[tt][i] = sval;
        mc[i] = fmaxf(mc[i], sval);
      }
    }
#pragma unroll
    for (int i = 0; i < 4; ++i)
#pragma unroll
      for (int off = 1; off < 16; off <<= 1) mc[i] = fmaxf(mc[i], __shfl_xor(mc[i], off, 64));
    float rs[4];
#pragma unroll
    for (int i = 0; i < 4; ++i) {
      float mn = fmaxf(mi[i], mc[i]);
      float sc = exp2f((mi[i] - mn) * LOG2E);
      mi[i] = mn; li[i] *= sc; rs[i] = 0.f;
      oa[0][i] *= sc; oa[1][i] *= sc; oa[2][i] *= sc; oa[3][i] *= sc;
#pragma unroll
      for (int tt = 0; tt < 4; ++tt) {
        float pe = exp2f((p[tt][i] - mn) * LOG2E);
        rs[i] += pe; p[tt][i] = pe;
      }
    }
#pragma unroll
    for (int i = 0; i < 4; ++i) {
#pragma unroll
      for (int off = 1; off < 16; off <<= 1) rs[i] += __shfl_xor(rs[i], off, 64);
      li[i] += rs[i];
    }
    // P -> LDS (bf16, swizzled), then PV
#pragma unroll
    for (int tt = 0; tt < 4; ++tt)
#pragma unroll
      for (int i = 0; i < 4; ++i) {
        int prow = lq * 4 + i;
        int cb = (tt * 16 + l15) * 2;
        *(u16*)((char*)PSW + prow * 128 + (cb ^ ((prow & 7) << 4))) = f2bf(p[tt][i]);
      }
    bf16x8 pa0, pa1;
    {
      int prow = l15, r7 = (prow & 7) << 4;
      pa0 = *(const bf16x8*)((char*)PSW + prow * 128 + ((lq * 16) ^ r7));
      pa1 = *(const bf16x8*)((char*)PSW + prow * 128 + (((4 | lq) * 16) ^ r7));
    }
#pragma unroll
    for (int ct = 0; ct < 4; ++ct) {
      int row = ct * 16 + l15, r7 = row & 7;
      bf16x8 bv0 = *(const bf16x8*)&VS[row * 64 + ((lq ^ r7) * 8)];
      bf16x8 bv1 = *(const bf16x8*)&VS[row * 64 + (((4 | lq) ^ r7) * 8)];
      oa[ct] = mfma16(pa0, bv0, oa[ct]);
      oa[ct] = mfma16(pa1, bv1, oa[ct]);
    }
  }
  u16* aop = ao + ((size_t)(n * 2048)) * 1024 + h * 64;
#pragma unroll
  for (int i = 0; i < 4; ++i) {
    float inv = 1.0f / li[i];
    int q = q0 + lq * 4 + i;
#pragma unroll
    for (int ct = 0; ct < 4; ++ct) {
      int dv = ct * 16 + l15;
      aop[(size_t)q * 1024 + dv] = f2bf(oa[ct][i] * inv);
    }
  }
}

extern "C" void kernel_launch(void* const* d_in, const int* in_sizes, int n_in,
                              void* d_out, int out_size, void* d_ws, size_t ws_size,
                              hipStream_t stream) {
  const float* q_in = (const float*)d_in[0];
  const float* k_in = (const float*)d_in[1];
  const float* v_in = (const float*)d_in[2];
  const float* ln_w = (const float*)d_in[3];
  const float* ln_b = (const float*)d_in[4];
  const float* Wq = (const float*)d_in[5];
  const float* Wk = (const float*)d_in[6];
  const float* Wv = (const float*)d_in[7];
  const float* Wo = (const float*)d_in[8];
  const float* Wkc = (const float*)d_in[9];
  const float* bkc = (const float*)d_in[10];
  const float* Wvc = (const float*)d_in[11];
  const float* bvc = (const float*)d_in[12];

  char* ws = (char*)d_ws;
  const size_t MB = 1u << 20;
  u16* wqe = (u16*)(ws + 0 * MB);
  u16* wkb = (u16*)(ws + 2 * MB);
  u16* wvb = (u16*)(ws + 4 * MB);
  u16* wob = (u16*)(ws + 6 * MB);
  u16* wkcb = (u16*)(ws + 8 * MB);
  u16* wvcb = (u16*)(ws + 10 * MB);
  float* cost = (float*)(ws + 12 * MB);
  float* sint = (float*)(ws + 12 * MB + 262144);
  u16* xn = (u16*)(ws + 13 * MB);    // 32MB, reused per tensor
  u16* qcb = (u16*)(ws + 45 * MB);   // 32MB
  u16* khb = (u16*)(ws + 77 * MB);   // 32MB
  u16* vhb = (u16*)(ws + 109 * MB);  // 32MB
  u16* kp = (u16*)(ws + 141 * MB);   // 9.0MB
  u16* vtp = (u16*)(ws + 141 * MB + 9437184);
  u16* aob = khb;                    // kh dead once attention runs

  // weight prep
  prep_wqe_kernel<<<1024, 256, 0, stream>>>(Wq, wqe);
  cast_w_kernel<<<1024, 256, 0, stream>>>(Wk, wkb);
  cast_w_kernel<<<1024, 256, 0, stream>>>(Wv, wvb);
  cast_w_kernel<<<1024, 256, 0, stream>>>(Wo, wob);
  cast_w_kernel<<<1024, 256, 0, stream>>>(Wkc, wkcb);
  cast_w_kernel<<<1024, 256, 0, stream>>>(Wvc, wvcb);
  rope_table_kernel<<<256, 256, 0, stream>>>(cost, sint);

  dim3 gg(8, 128);
  // q: LN -> GEMM(Wq_eff)
  ln_kernel<<<16384, 256, 0, stream>>>(q_in, ln_w, ln_b, xn);
  gemm_nt<0><<<gg, 256, 0, stream>>>(xn, wqe, qcb, 16384, 1024, 1024);
  // k
  ln_kernel<<<16384, 256, 0, stream>>>(k_in, ln_w, ln_b, xn);
  gemm_nt<0><<<gg, 256, 0, stream>>>(xn, wkb, khb, 16384, 1024, 1024);
  // v
  ln_kernel<<<16384, 256, 0, stream>>>(v_in, ln_w, ln_b, xn);
  gemm_nt<0><<<gg, 256, 0, stream>>>(xn, wvb, vhb, 16384, 1024, 1024);

  rope_kernel<<<16384, 256, 0, stream>>>(qcb, khb, cost, sint);
  compress_mfma_kernel<<<dim3(48, 2), 512, 0, stream>>>(khb, vhb, wkcb, wvcb, bkc, bvc, kp, vtp);
  copy_recent_kernel<<<4584, 256, 0, stream>>>(khb, vhb, kp, vtp);
  attn_kernel<<<dim3(32, 16, 8), 256, 0, stream>>>(qcb, kp, vtp, aob);
  gemm_nt<1><<<gg, 256, 0, stream>>>(aob, wob, (float*)d_out, 16384, 1024, 1024);
}

// Round 3
// 540.293 us; speedup vs baseline: 1.6820x; 1.2334x over previous
//
#include <hip/hip_runtime.h>
#include <stdint.h>

#define DEV static __device__ __forceinline__

typedef unsigned short u16;
typedef unsigned int u32;
typedef __attribute__((ext_vector_type(4))) float f32x4;
typedef __attribute__((ext_vector_type(8))) short bf16x8;

DEV float bf2f(u16 u) { u32 x = ((u32)u) << 16; float f; __builtin_memcpy(&f, &x, 4); return f; }
DEV u16 f2bf(float f) { u32 x; __builtin_memcpy(&x, &f, 4); x = x + 0x7fffu + ((x >> 16) & 1u); return (u16)(x >> 16); }
DEV float lo16(u32 p) { u32 x = p << 16; float f; __builtin_memcpy(&f, &x, 4); return f; }
DEV float hi16(u32 p) { u32 x = p & 0xffff0000u; float f; __builtin_memcpy(&f, &x, 4); return f; }
DEV u32 pack2(float a, float b) { return (u32)f2bf(a) | ((u32)f2bf(b) << 16); }

DEV f32x4 mfma16(bf16x8 a, bf16x8 b, f32x4 c) {
  return __builtin_amdgcn_mfma_f32_16x16x32_bf16(a, b, c, 0, 0, 0);
}

DEV void gl_lds16(const u16* g, u16* l) {
  __builtin_amdgcn_global_load_lds((const __attribute__((address_space(1))) void*)g,
                                   (__attribute__((address_space(3))) void*)l, 16, 0, 0);
}

// ---------------- weight prep ----------------
// Wq_eff = Wq[g=0] + Wq[g=1] (group-sum folded into projection), cast bf16
__global__ __launch_bounds__(256) void prep_wqe_kernel(const float* __restrict__ Wq, u16* __restrict__ out) {
  int id = blockIdx.x * 256 + threadIdx.x;           // 262144 float4 units
  float4 a = ((const float4*)Wq)[id];
  float4 b = ((const float4*)Wq)[id + 262144];       // +1024*1024 floats
  ushort4 o; o.x = f2bf(a.x + b.x); o.y = f2bf(a.y + b.y); o.z = f2bf(a.z + b.z); o.w = f2bf(a.w + b.w);
  ((ushort4*)out)[id] = o;
}

__global__ __launch_bounds__(256) void cast_w_kernel(const float* __restrict__ src, u16* __restrict__ dst) {
  int id = blockIdx.x * 256 + threadIdx.x;
  float4 a = ((const float4*)src)[id];
  ushort4 o; o.x = f2bf(a.x); o.y = f2bf(a.y); o.z = f2bf(a.z); o.w = f2bf(a.w);
  ((ushort4*)dst)[id] = o;
}

__global__ __launch_bounds__(256) void rope_table_kernel(float* __restrict__ ct, float* __restrict__ st) {
  int id = blockIdx.x * 256 + threadIdx.x;           // 2048*32
  int t = id >> 5, i = id & 31;
  double ang = (double)t * pow(10000.0, -(double)(2 * i) / 64.0);
  ct[id] = (float)cos(ang);
  st[id] = (float)sin(ang);
}

// ---------------- layernorm (one block per 1024-row) ----------------
__global__ __launch_bounds__(256) void ln_kernel(const float* __restrict__ x, const float* __restrict__ w,
                                                 const float* __restrict__ b, u16* __restrict__ out) {
  int row = blockIdx.x, t = threadIdx.x;
  float4 v = ((const float4*)(x + (size_t)row * 1024))[t];
  float s = v.x + v.y + v.z + v.w;
  float s2 = v.x * v.x + v.y * v.y + v.z * v.z + v.w * v.w;
#pragma unroll
  for (int off = 32; off; off >>= 1) { s += __shfl_xor(s, off, 64); s2 += __shfl_xor(s2, off, 64); }
  __shared__ float red[8];
  if ((t & 63) == 0) { red[t >> 6] = s; red[4 + (t >> 6)] = s2; }
  __syncthreads();
  s = red[0] + red[1] + red[2] + red[3];
  s2 = red[4] + red[5] + red[6] + red[7];
  float mu = s * 0.0009765625f;
  float var = s2 * 0.0009765625f - mu * mu;
  float rstd = rsqrtf(var + 1e-5f);
  float4 wv = ((const float4*)w)[t];
  float4 bv = ((const float4*)b)[t];
  ushort4 o;
  o.x = f2bf((v.x - mu) * rstd * wv.x + bv.x);
  o.y = f2bf((v.y - mu) * rstd * wv.y + bv.y);
  o.z = f2bf((v.z - mu) * rstd * wv.z + bv.z);
  o.w = f2bf((v.w - mu) * rstd * wv.w + bv.w);
  *(ushort4*)(out + (size_t)row * 1024 + t * 4) = o;
}

// ---------------- NT GEMM: C[m][n] = sum_k A[m*K+k]*B[n*K+k]  (m97-style 128x128, BK=32) ----------------
template <int OUTF32>
__global__ __launch_bounds__(256, 2) void gemm_nt(const u16* __restrict__ A, const u16* __restrict__ B,
                                                  void* __restrict__ Cout, int M, int Nd, int K) {
  __shared__ u16 As[4096], Bs[4096];                 // [128 rows][32 k] each, quarter-XOR-swizzled
  int tid = threadIdx.x, lane = tid & 63, wv = tid >> 6;
  int l15 = lane & 15, lq = lane >> 4;
  int bm = blockIdx.y * 128, bn = blockIdx.x * 128;
  int wm = (wv >> 1) * 64, wn = (wv & 1) * 64;
  f32x4 acc[4][4] = {};
  for (int k0 = 0; k0 < K; k0 += 32) {
    __syncthreads();                                 // previous iter's LDS reads done
#pragma unroll
    for (int it = 0; it < 2; ++it) {
      int ia = wv * 2 + it;                          // 8 1KB slabs per tile
      int row = ia * 16 + (lane >> 2);
      int qs = lane & 3;
      int qg = qs ^ (row & 3);                       // pre-swizzled global quarter
      gl_lds16(A + (size_t)(bm + row) * K + k0 + qg * 8, &As[ia * 512]);
      gl_lds16(B + (size_t)(bn + row) * K + k0 + qg * 8, &Bs[ia * 512]);
    }
    __syncthreads();                                 // vmcnt(0) drain before use
    bf16x8 af[4], bfr[4];
#pragma unroll
    for (int mt = 0; mt < 4; ++mt) {
      int r = wm + mt * 16 + l15;
      af[mt] = *(const bf16x8*)&As[r * 32 + ((lq ^ (r & 3)) * 8)];
    }
#pragma unroll
    for (int nt = 0; nt < 4; ++nt) {
      int r = wn + nt * 16 + l15;
      bfr[nt] = *(const bf16x8*)&Bs[r * 32 + ((lq ^ (r & 3)) * 8)];
    }
#pragma unroll
    for (int mt = 0; mt < 4; ++mt)
#pragma unroll
      for (int nt = 0; nt < 4; ++nt)
        acc[mt][nt] = mfma16(af[mt], bfr[nt], acc[mt][nt]);
  }
#pragma unroll
  for (int mt = 0; mt < 4; ++mt)
#pragma unroll
    for (int nt = 0; nt < 4; ++nt)
#pragma unroll
      for (int i = 0; i < 4; ++i) {
        int row = bm + wm + mt * 16 + lq * 4 + i;
        int col = bn + wn + nt * 16 + l15;
        if (OUTF32) ((float*)Cout)[(size_t)row * Nd + col] = acc[mt][nt][i];
        else ((u16*)Cout)[(size_t)row * Nd + col] = f2bf(acc[mt][nt][i]);
      }
}

// ---------------- RoPE in place on qc and kh ([16384][1024] bf16, 64-col heads, interleaved pairs) -------
__global__ __launch_bounds__(256) void rope_kernel(u16* __restrict__ qc, u16* __restrict__ kh,
                                                   const float* __restrict__ ct, const float* __restrict__ st) {
  u32 id = blockIdx.x * 256 + threadIdx.x;
  u16* base = qc;
  if (id >= 2097152u) { base = kh; id -= 2097152u; }
  size_t e0 = (size_t)id * 8;
  int row = (int)(e0 >> 10);
  int col = (int)(e0 & 1023);
  int t = row & 2047;
  int i0 = (col & 63) >> 1;                          // multiple of 4
  float4 c = *(const float4*)(ct + t * 32 + i0);
  float4 s = *(const float4*)(st + t * 32 + i0);
  uint4 u = *(const uint4*)(base + e0);
  float x0 = lo16(u.x), x1 = hi16(u.x), x2 = lo16(u.y), x3 = hi16(u.y);
  float x4 = lo16(u.z), x5 = hi16(u.z), x6 = lo16(u.w), x7 = hi16(u.w);
  uint4 o;
  o.x = pack2(x0 * c.x - x1 * s.x, x1 * c.x + x0 * s.x);
  o.y = pack2(x2 * c.y - x3 * s.y, x3 * c.y + x2 * s.y);
  o.z = pack2(x4 * c.z - x5 * s.z, x5 * c.z + x4 * s.z);
  o.w = pack2(x6 * c.w - x7 * s.w, x7 * c.w + x6 * s.w);
  *(uint4*)(base + e0) = o;
}

// ---------------- segment compression as MFMA GEMM ----------------
__global__ __launch_bounds__(512) void compress_mfma_kernel(
    const u16* __restrict__ kh, const u16* __restrict__ vh,
    const u16* __restrict__ wkcb, const u16* __restrict__ wvcb,
    const float* __restrict__ bkc, const float* __restrict__ bvc,
    u16* __restrict__ kp, u16* __restrict__ vtp) {
  int mt = blockIdx.x, kv = blockIdx.y;
  const u16* src = kv ? vh : kh;
  const u16* W = kv ? wvcb : wkcb;
  int tid = threadIdx.x, lane = tid & 63, wv = tid >> 6;
  int l15 = lane & 15, lq = lane >> 4;
  int r = mt * 16 + l15;                             // row in [0,768)
  int nh = r / 6, s = r % 6;
  int n = nh >> 4, h = nh & 15;
  const u16* arow = src + ((size_t)(n * 2048 + s * 256)) * 1024 + h * 64;
  f32x4 acc[4] = {};
  int kbase = wv * 2048;
#pragma unroll 4
  for (int ks = 0; ks < 64; ++ks) {
    int k0 = kbase + ks * 32;
    int tau = k0 >> 6, d0 = k0 & 63;
    bf16x8 a = *(const bf16x8*)(arow + (size_t)tau * 1024 + d0 + lq * 8);
#pragma unroll
    for (int nt = 0; nt < 4; ++nt) {
      bf16x8 b = *(const bf16x8*)(W + (size_t)(nt * 16 + l15) * 16384 + k0 + lq * 8);
      acc[nt] = mfma16(a, b, acc[nt]);
    }
  }
  __shared__ float red[8][16][64];
#pragma unroll
  for (int nt = 0; nt < 4; ++nt)
#pragma unroll
    for (int i = 0; i < 4; ++i)
      red[wv][lq * 4 + i][nt * 16 + l15] = acc[nt][i];
  __syncthreads();
  int row = tid >> 5, o0 = (tid & 31) * 2;
  int rr = mt * 16 + row;
  int nh2 = rr / 6, s2 = rr % 6;
#pragma unroll
  for (int j = 0; j < 2; ++j) {
    int o = o0 + j;
    float v = (kv ? bvc[o] : bkc[o]);
#pragma unroll
    for (int w8 = 0; w8 < 8; ++w8) v += red[w8][row][o];
    v = v > 0.f ? v : expm1f(v);                     // elu
    if (kv) vtp[((size_t)nh2 * 64 + o) * 576 + s2] = f2bf(v);
    else    kp[((size_t)nh2 * 576 + s2) * 64 + o] = f2bf(v);
  }
}

// ---------------- copy recent 512 rows into packed K [nh][576][64] and V^T [nh][64][576]; zero pad ------
__global__ __launch_bounds__(256) void copy_recent_kernel(const u16* __restrict__ kh, const u16* __restrict__ vh,
                                                          u16* __restrict__ kp, u16* __restrict__ vtp) {
  int bid = blockIdx.x;
  if (bid < 2280) {                                  // K rows T=6..575
    int u = bid * 256 + threadIdx.x;                 // = (nh*570 + (T-6))*8 + dq8
    int dq8 = u & 7; int rest = u >> 3; int Tm6 = rest % 570; int nh = rest / 570;
    if (nh >= 128) return;
    uint4 val = {0, 0, 0, 0};
    if (Tm6 < 512) {
      int n = nh >> 4, h = nh & 15;
      val = *(const uint4*)&kh[((size_t)(n * 2048 + 1536 + Tm6)) * 1024 + h * 64 + dq8 * 8];
    }
    *(uint4*)&kp[((size_t)nh * 576 + 6 + Tm6) * 64 + dq8 * 8] = val;
  } else {                                           // V^T cols
    int u = (bid - 2280) * 256 + threadIdx.x;        // = (nh*72 + tch)*64 + d
    int d = u & 63; int rest = u >> 6; int tch = rest % 72; int nh = rest / 72;
    if (nh >= 128) return;
    int n = nh >> 4, h = nh & 15;
#pragma unroll
    for (int ii = 0; ii < 8; ++ii) {
      int T = tch * 8 + ii;
      if (T < 6) continue;                           // written by compression
      u16 v = 0;
      if (T < 518) v = vh[((size_t)(n * 2048 + 1536 + (T - 6))) * 1024 + h * 64 + d];
      vtp[((size_t)nh * 64 + d) * 576 + T] = v;
    }
  }
}

// ---------------- fused attention: per (n,h,64 q-rows); flash over causal chunks of 64 T ----------------
// Logits are bounded: 30*tanh(x) <= 30, so softmax uses FIXED max = 30 -> no online rescale,
// no per-chunk cross-lane reductions. pe = exp(s-30) = exp2(C2 / (exp2(C1*sv)+1)), 6 VALU/logit.
__global__ __launch_bounds__(256) void attn_kernel(const u16* __restrict__ qc, const u16* __restrict__ Kp,
                                                   const u16* __restrict__ VTp, u16* __restrict__ ao) {
  int qt = blockIdx.x, h = blockIdx.y, n = blockIdx.z;
  int tid = threadIdx.x, lane = tid & 63, wv = tid >> 6;
  int l15 = lane & 15, lq = lane >> 4;
  __shared__ u16 KS[4096], VS[4096];                 // 64x64 bf16 chunks, row-XOR-swizzled
  __shared__ u16 PS[4][1024];                        // per-wave P [16][64] bf16 (2KB each)
  int q0 = qt * 64 + wv * 16;
  const u16* qrowp = qc + ((size_t)(n * 2048 + q0 + l15)) * 1024 + h * 64;
  bf16x8 aq0 = *(const bf16x8*)(qrowp + lq * 8);
  bf16x8 aq1 = *(const bf16x8*)(qrowp + 32 + lq * 8);
  const u16* Kph = Kp + (size_t)(n * 16 + h) * 576 * 64;
  const u16* Vph = VTp + (size_t)(n * 16 + h) * 64 * 576;
  f32x4 oa[4] = {};
  float rs[4] = {0.f, 0.f, 0.f, 0.f};
  u16* PSW = &PS[wv][0];
  const float C1 = 0.012022458674074693f;            // 0.125 * (2/30) * log2(e)
  const float C2 = -86.56170245333781f;              // -60 * log2(e)
  int nchunks = min(qt + 1, 9);                      // causal skip: chunk tc covers T < (tc+1)*64
  for (int tc = 0; tc < nchunks; ++tc) {
    int Tbase = tc * 64;
    __syncthreads();
#pragma unroll
    for (int it = 0; it < 2; ++it) {                 // stage K,V chunk (8KB each)
      int slot = it * 256 + tid;                     // 0..511 16B slots
      int row = slot >> 3, qq = slot & 7;
      int sw = (qq ^ (row & 7)) * 8;
      *(uint4*)&KS[row * 64 + sw] = *(const uint4*)&Kph[(size_t)(Tbase + row) * 64 + qq * 8];
      *(uint4*)&VS[row * 64 + sw] = *(const uint4*)&Vph[(size_t)row * 576 + Tbase + qq * 8];
    }
    __syncthreads();
    // S = Q @ K^T for 16 q-rows x 64 T
    f32x4 sv[4];
#pragma unroll
    for (int tt = 0; tt < 4; ++tt) {
      int row = tt * 16 + l15, r7 = row & 7;
      bf16x8 b0 = *(const bf16x8*)&KS[row * 64 + ((lq ^ r7) * 8)];
      bf16x8 b1 = *(const bf16x8*)&KS[row * 64 + (((4 | lq) ^ r7) * 8)];
      f32x4 c = {0.f, 0.f, 0.f, 0.f};
      c = mfma16(aq0, b0, c);
      c = mfma16(aq1, b1, c);
      sv[tt] = c;
    }
    float p[4][4];
    bool needmask = (tc == qt) || (tc == 8);
    if (needmask) {
      int qb = q0 + lq * 4;
#pragma unroll
      for (int tt = 0; tt < 4; ++tt) {
        int T = Tbase + tt * 16 + l15;
        bool tval = (T < 518);
#pragma unroll
        for (int i = 0; i < 4; ++i) {
          float e = __builtin_amdgcn_exp2f(sv[tt][i] * C1);
          float pe = __builtin_amdgcn_exp2f(C2 * __builtin_amdgcn_rcpf(e + 1.f));
          bool ok = tval && (T <= qb + i);
          pe = ok ? pe : 0.f;
          p[tt][i] = pe;
          rs[i] += pe;
        }
      }
    } else {
#pragma unroll
      for (int tt = 0; tt < 4; ++tt)
#pragma unroll
        for (int i = 0; i < 4; ++i) {
          float e = __builtin_amdgcn_exp2f(sv[tt][i] * C1);
          float pe = __builtin_amdgcn_exp2f(C2 * __builtin_amdgcn_rcpf(e + 1.f));
          p[tt][i] = pe;
          rs[i] += pe;
        }
    }
    // P -> LDS (bf16, swizzled), then PV
#pragma unroll
    for (int tt = 0; tt < 4; ++tt)
#pragma unroll
      for (int i = 0; i < 4; ++i) {
        int prow = lq * 4 + i;
        int cb = (tt * 16 + l15) * 2;
        *(u16*)((char*)PSW + prow * 128 + (cb ^ ((prow & 7) << 4))) = f2bf(p[tt][i]);
      }
    bf16x8 pa0, pa1;
    {
      int prow = l15, r7 = (prow & 7) << 4;
      pa0 = *(const bf16x8*)((char*)PSW + prow * 128 + ((lq * 16) ^ r7));
      pa1 = *(const bf16x8*)((char*)PSW + prow * 128 + (((4 | lq) * 16) ^ r7));
    }
#pragma unroll
    for (int ct = 0; ct < 4; ++ct) {
      int row = ct * 16 + l15, r7 = row & 7;
      bf16x8 bv0 = *(const bf16x8*)&VS[row * 64 + ((lq ^ r7) * 8)];
      bf16x8 bv1 = *(const bf16x8*)&VS[row * 64 + (((4 | lq) ^ r7) * 8)];
      oa[ct] = mfma16(pa0, bv0, oa[ct]);
      oa[ct] = mfma16(pa1, bv1, oa[ct]);
    }
  }
  // one final cross-lane sum for the denominators (lanes differing in bits 0-3 share lq)
#pragma unroll
  for (int i = 0; i < 4; ++i)
#pragma unroll
    for (int off = 1; off < 16; off <<= 1) rs[i] += __shfl_xor(rs[i], off, 64);
  u16* aop = ao + ((size_t)(n * 2048)) * 1024 + h * 64;
#pragma unroll
  for (int i = 0; i < 4; ++i) {
    float inv = 1.0f / rs[i];
    int q = q0 + lq * 4 + i;
#pragma unroll
    for (int ct = 0; ct < 4; ++ct) {
      int dv = ct * 16 + l15;
      aop[(size_t)q * 1024 + dv] = f2bf(oa[ct][i] * inv);
    }
  }
}

extern "C" void kernel_launch(void* const* d_in, const int* in_sizes, int n_in,
                              void* d_out, int out_size, void* d_ws, size_t ws_size,
                              hipStream_t stream) {
  const float* q_in = (const float*)d_in[0];
  const float* k_in = (const float*)d_in[1];
  const float* v_in = (const float*)d_in[2];
  const float* ln_w = (const float*)d_in[3];
  const float* ln_b = (const float*)d_in[4];
  const float* Wq = (const float*)d_in[5];
  const float* Wk = (const float*)d_in[6];
  const float* Wv = (const float*)d_in[7];
  const float* Wo = (const float*)d_in[8];
  const float* Wkc = (const float*)d_in[9];
  const float* bkc = (const float*)d_in[10];
  const float* Wvc = (const float*)d_in[11];
  const float* bvc = (const float*)d_in[12];

  char* ws = (char*)d_ws;
  const size_t MB = 1u << 20;
  u16* wqe = (u16*)(ws + 0 * MB);
  u16* wkb = (u16*)(ws + 2 * MB);
  u16* wvb = (u16*)(ws + 4 * MB);
  u16* wob = (u16*)(ws + 6 * MB);
  u16* wkcb = (u16*)(ws + 8 * MB);
  u16* wvcb = (u16*)(ws + 10 * MB);
  float* cost = (float*)(ws + 12 * MB);
  float* sint = (float*)(ws + 12 * MB + 262144);
  u16* xn = (u16*)(ws + 13 * MB);    // 32MB, reused per tensor
  u16* qcb = (u16*)(ws + 45 * MB);   // 32MB
  u16* khb = (u16*)(ws + 77 * MB);   // 32MB
  u16* vhb = (u16*)(ws + 109 * MB);  // 32MB
  u16* kp = (u16*)(ws + 141 * MB);   // 9.0MB
  u16* vtp = (u16*)(ws + 141 * MB + 9437184);
  u16* aob = khb;                    // kh dead once attention runs

  // weight prep
  prep_wqe_kernel<<<1024, 256, 0, stream>>>(Wq, wqe);
  cast_w_kernel<<<1024, 256, 0, stream>>>(Wk, wkb);
  cast_w_kernel<<<1024, 256, 0, stream>>>(Wv, wvb);
  cast_w_kernel<<<1024, 256, 0, stream>>>(Wo, wob);
  cast_w_kernel<<<1024, 256, 0, stream>>>(Wkc, wkcb);
  cast_w_kernel<<<1024, 256, 0, stream>>>(Wvc, wvcb);
  rope_table_kernel<<<256, 256, 0, stream>>>(cost, sint);

  dim3 gg(8, 128);
  // q: LN -> GEMM(Wq_eff)
  ln_kernel<<<16384, 256, 0, stream>>>(q_in, ln_w, ln_b, xn);
  gemm_nt<0><<<gg, 256, 0, stream>>>(xn, wqe, qcb, 16384, 1024, 1024);
  // k
  ln_kernel<<<16384, 256, 0, stream>>>(k_in, ln_w, ln_b, xn);
  gemm_nt<0><<<gg, 256, 0, stream>>>(xn, wkb, khb, 16384, 1024, 1024);
  // v
  ln_kernel<<<16384, 256, 0, stream>>>(v_in, ln_w, ln_b, xn);
  gemm_nt<0><<<gg, 256, 0, stream>>>(xn, wvb, vhb, 16384, 1024, 1024);

  rope_kernel<<<16384, 256, 0, stream>>>(qcb, khb, cost, sint);
  compress_mfma_kernel<<<dim3(48, 2), 512, 0, stream>>>(khb, vhb, wkcb, wvcb, bkc, bvc, kp, vtp);
  copy_recent_kernel<<<4584, 256, 0, stream>>>(khb, vhb, kp, vtp);
  attn_kernel<<<dim3(32, 16, 8), 256, 0, stream>>>(qcb, kp, vtp, aob);
  gemm_nt<1><<<gg, 256, 0, stream>>>(aob, wob, (float*)d_out, 16384, 1024, 1024);
}

// Round 4
// 472.834 us; speedup vs baseline: 1.9220x; 1.1427x over previous
//
#include <hip/hip_runtime.h>
#include <stdint.h>

#define DEV static __device__ __forceinline__

typedef unsigned short u16;
typedef unsigned int u32;
typedef __attribute__((ext_vector_type(4))) float f32x4;
typedef __attribute__((ext_vector_type(8))) short bf16x8;

DEV float bf2f(u16 u) { u32 x = ((u32)u) << 16; float f; __builtin_memcpy(&f, &x, 4); return f; }
DEV u16 f2bf(float f) { u32 x; __builtin_memcpy(&x, &f, 4); x = x + 0x7fffu + ((x >> 16) & 1u); return (u16)(x >> 16); }
DEV float lo16(u32 p) { u32 x = p << 16; float f; __builtin_memcpy(&f, &x, 4); return f; }
DEV float hi16(u32 p) { u32 x = p & 0xffff0000u; float f; __builtin_memcpy(&f, &x, 4); return f; }
DEV u32 pack2(float a, float b) { return (u32)f2bf(a) | ((u32)f2bf(b) << 16); }

DEV f32x4 mfma16(bf16x8 a, bf16x8 b, f32x4 c) {
  return __builtin_amdgcn_mfma_f32_16x16x32_bf16(a, b, c, 0, 0, 0);
}

DEV void gl_lds16(const u16* g, u16* l) {
  __builtin_amdgcn_global_load_lds((const __attribute__((address_space(1))) void*)g,
                                   (__attribute__((address_space(3))) void*)l, 16, 0, 0);
}

// ---------------- weight prep ----------------
// Wq_eff = Wq[g=0] + Wq[g=1] (group-sum folded into projection), cast bf16
__global__ __launch_bounds__(256) void prep_wqe_kernel(const float* __restrict__ Wq, u16* __restrict__ out) {
  int id = blockIdx.x * 256 + threadIdx.x;           // 262144 float4 units
  float4 a = ((const float4*)Wq)[id];
  float4 b = ((const float4*)Wq)[id + 262144];       // +1024*1024 floats
  ushort4 o; o.x = f2bf(a.x + b.x); o.y = f2bf(a.y + b.y); o.z = f2bf(a.z + b.z); o.w = f2bf(a.w + b.w);
  ((ushort4*)out)[id] = o;
}

__global__ __launch_bounds__(256) void cast_w_kernel(const float* __restrict__ src, u16* __restrict__ dst) {
  int id = blockIdx.x * 256 + threadIdx.x;
  float4 a = ((const float4*)src)[id];
  ushort4 o; o.x = f2bf(a.x); o.y = f2bf(a.y); o.z = f2bf(a.z); o.w = f2bf(a.w);
  ((ushort4*)dst)[id] = o;
}

__global__ __launch_bounds__(256) void rope_table_kernel(float* __restrict__ ct, float* __restrict__ st) {
  int id = blockIdx.x * 256 + threadIdx.x;           // 2048*32
  int t = id >> 5, i = id & 31;
  double ang = (double)t * pow(10000.0, -(double)(2 * i) / 64.0);
  ct[id] = (float)cos(ang);
  st[id] = (float)sin(ang);
}

// ---------------- layernorm (one block per 1024-row) ----------------
__global__ __launch_bounds__(256) void ln_kernel(const float* __restrict__ x, const float* __restrict__ w,
                                                 const float* __restrict__ b, u16* __restrict__ out) {
  int row = blockIdx.x, t = threadIdx.x;
  float4 v = ((const float4*)(x + (size_t)row * 1024))[t];
  float s = v.x + v.y + v.z + v.w;
  float s2 = v.x * v.x + v.y * v.y + v.z * v.z + v.w * v.w;
#pragma unroll
  for (int off = 32; off; off >>= 1) { s += __shfl_xor(s, off, 64); s2 += __shfl_xor(s2, off, 64); }
  __shared__ float red[8];
  if ((t & 63) == 0) { red[t >> 6] = s; red[4 + (t >> 6)] = s2; }
  __syncthreads();
  s = red[0] + red[1] + red[2] + red[3];
  s2 = red[4] + red[5] + red[6] + red[7];
  float mu = s * 0.0009765625f;
  float var = s2 * 0.0009765625f - mu * mu;
  float rstd = rsqrtf(var + 1e-5f);
  float4 wv = ((const float4*)w)[t];
  float4 bv = ((const float4*)b)[t];
  ushort4 o;
  o.x = f2bf((v.x - mu) * rstd * wv.x + bv.x);
  o.y = f2bf((v.y - mu) * rstd * wv.y + bv.y);
  o.z = f2bf((v.z - mu) * rstd * wv.z + bv.z);
  o.w = f2bf((v.w - mu) * rstd * wv.w + bv.w);
  *(ushort4*)(out + (size_t)row * 1024 + t * 4) = o;
}

// ---------------- NT GEMM: C[m][n] = sum_k A[m*K+k]*B[n*K+k]  (m97-style 128x128, BK=32) ----------------
template <int OUTF32>
__global__ __launch_bounds__(256, 2) void gemm_nt(const u16* __restrict__ A, const u16* __restrict__ B,
                                                  void* __restrict__ Cout, int M, int Nd, int K) {
  __shared__ u16 As[4096], Bs[4096];                 // [128 rows][32 k] each, quarter-XOR-swizzled
  int tid = threadIdx.x, lane = tid & 63, wv = tid >> 6;
  int l15 = lane & 15, lq = lane >> 4;
  int bm = blockIdx.y * 128, bn = blockIdx.x * 128;
  int wm = (wv >> 1) * 64, wn = (wv & 1) * 64;
  f32x4 acc[4][4] = {};
  for (int k0 = 0; k0 < K; k0 += 32) {
    __syncthreads();                                 // previous iter's LDS reads done
#pragma unroll
    for (int it = 0; it < 2; ++it) {
      int ia = wv * 2 + it;                          // 8 1KB slabs per tile
      int row = ia * 16 + (lane >> 2);
      int qs = lane & 3;
      int qg = qs ^ (row & 3);                       // pre-swizzled global quarter
      gl_lds16(A + (size_t)(bm + row) * K + k0 + qg * 8, &As[ia * 512]);
      gl_lds16(B + (size_t)(bn + row) * K + k0 + qg * 8, &Bs[ia * 512]);
    }
    __syncthreads();                                 // vmcnt(0) drain before use
    bf16x8 af[4], bfr[4];
#pragma unroll
    for (int mt = 0; mt < 4; ++mt) {
      int r = wm + mt * 16 + l15;
      af[mt] = *(const bf16x8*)&As[r * 32 + ((lq ^ (r & 3)) * 8)];
    }
#pragma unroll
    for (int nt = 0; nt < 4; ++nt) {
      int r = wn + nt * 16 + l15;
      bfr[nt] = *(const bf16x8*)&Bs[r * 32 + ((lq ^ (r & 3)) * 8)];
    }
#pragma unroll
    for (int mt = 0; mt < 4; ++mt)
#pragma unroll
      for (int nt = 0; nt < 4; ++nt)
        acc[mt][nt] = mfma16(af[mt], bfr[nt], acc[mt][nt]);
  }
#pragma unroll
  for (int mt = 0; mt < 4; ++mt)
#pragma unroll
    for (int nt = 0; nt < 4; ++nt)
#pragma unroll
      for (int i = 0; i < 4; ++i) {
        int row = bm + wm + mt * 16 + lq * 4 + i;
        int col = bn + wn + nt * 16 + l15;
        if (OUTF32) ((float*)Cout)[(size_t)row * Nd + col] = acc[mt][nt][i];
        else ((u16*)Cout)[(size_t)row * Nd + col] = f2bf(acc[mt][nt][i]);
      }
}

// ---------------- RoPE in place on qc and kh ([16384][1024] bf16, 64-col heads, interleaved pairs) -------
__global__ __launch_bounds__(256) void rope_kernel(u16* __restrict__ qc, u16* __restrict__ kh,
                                                   const float* __restrict__ ct, const float* __restrict__ st) {
  u32 id = blockIdx.x * 256 + threadIdx.x;
  u16* base = qc;
  if (id >= 2097152u) { base = kh; id -= 2097152u; }
  size_t e0 = (size_t)id * 8;
  int row = (int)(e0 >> 10);
  int col = (int)(e0 & 1023);
  int t = row & 2047;
  int i0 = (col & 63) >> 1;                          // multiple of 4
  float4 c = *(const float4*)(ct + t * 32 + i0);
  float4 s = *(const float4*)(st + t * 32 + i0);
  uint4 u = *(const uint4*)(base + e0);
  float x0 = lo16(u.x), x1 = hi16(u.x), x2 = lo16(u.y), x3 = hi16(u.y);
  float x4 = lo16(u.z), x5 = hi16(u.z), x6 = lo16(u.w), x7 = hi16(u.w);
  uint4 o;
  o.x = pack2(x0 * c.x - x1 * s.x, x1 * c.x + x0 * s.x);
  o.y = pack2(x2 * c.y - x3 * s.y, x3 * c.y + x2 * s.y);
  o.z = pack2(x4 * c.z - x5 * s.z, x5 * c.z + x4 * s.z);
  o.w = pack2(x6 * c.w - x7 * s.w, x7 * c.w + x6 * s.w);
  *(uint4*)(base + e0) = o;
}

// ---------------- segment compression, split-K MFMA (stage 1: partials) ----------------
// out[768][64] = elu(X[768][16384] @ W[64][16384]^T + b), per kv.
// grid (48 m-tiles, 8 k-slices, 2 kv); 512 thr = 8 waves; wave wv covers K sub-slice of 256.
// Partials (f32) -> part[(kv*8+ksl)][row 768][64].
__global__ __launch_bounds__(512) void compress_partial_kernel(
    const u16* __restrict__ kh, const u16* __restrict__ vh,
    const u16* __restrict__ wkcb, const u16* __restrict__ wvcb,
    float* __restrict__ part) {
  int mt = blockIdx.x, ksl = blockIdx.y, kv = blockIdx.z;
  const u16* src = kv ? vh : kh;
  const u16* W = kv ? wvcb : wkcb;
  int tid = threadIdx.x, lane = tid & 63, wv = tid >> 6;
  int l15 = lane & 15, lq = lane >> 4;
  int r = mt * 16 + l15;                             // row in [0,768)
  int nh = r / 6, s = r % 6;
  int n = nh >> 4, h = nh & 15;
  const u16* arow = src + ((size_t)(n * 2048 + s * 256)) * 1024 + h * 64;
  f32x4 acc[4] = {};
  int kbase = (ksl * 8 + wv) * 256;
#pragma unroll
  for (int ks = 0; ks < 8; ++ks) {
    int k0 = kbase + ks * 32;
    int tau = k0 >> 6, d0 = k0 & 63;
    bf16x8 a = *(const bf16x8*)(arow + (size_t)tau * 1024 + d0 + lq * 8);
#pragma unroll
    for (int nt = 0; nt < 4; ++nt) {
      bf16x8 b = *(const bf16x8*)(W + (size_t)(nt * 16 + l15) * 16384 + k0 + lq * 8);
      acc[nt] = mfma16(a, b, acc[nt]);
    }
  }
  __shared__ float red[8][16][68];                   // 68-stride: 2-way bank alias only (free)
#pragma unroll
  for (int nt = 0; nt < 4; ++nt)
#pragma unroll
    for (int i = 0; i < 4; ++i)
      red[wv][lq * 4 + i][nt * 16 + l15] = acc[nt][i];
  __syncthreads();
  int row = tid >> 5, o0 = (tid & 31) * 2;           // 512 threads -> 16 rows x 32 pairs
  float v0 = 0.f, v1 = 0.f;
#pragma unroll
  for (int w8 = 0; w8 < 8; ++w8) { v0 += red[w8][row][o0]; v1 += red[w8][row][o0 + 1]; }
  size_t base = ((size_t)(kv * 8 + ksl) * 768 + mt * 16 + row) * 64 + o0;
  part[base] = v0;
  part[base + 1] = v1;
}

// stage 2: sum 8 k-slices, bias, elu, scatter to packed K [nh][576][64] / V^T [nh][64][576]
__global__ __launch_bounds__(256) void compress_finalize_kernel(
    const float* __restrict__ part, const float* __restrict__ bkc, const float* __restrict__ bvc,
    u16* __restrict__ kp, u16* __restrict__ vtp) {
  int id = blockIdx.x * 256 + threadIdx.x;           // [0, 49152)
  int kv = blockIdx.y;
  int r = id >> 6, o = id & 63;
  float v = kv ? bvc[o] : bkc[o];
#pragma unroll
  for (int s8 = 0; s8 < 8; ++s8) v += part[((size_t)(kv * 8 + s8) * 768 + r) * 64 + o];
  v = v > 0.f ? v : expm1f(v);                       // elu
  int nh = r / 6, s = r % 6;
  if (kv) vtp[((size_t)nh * 64 + o) * 576 + s] = f2bf(v);
  else    kp[((size_t)nh * 576 + s) * 64 + o] = f2bf(v);
}

// ---------------- copy recent 512 rows into packed K [nh][576][64] and V^T [nh][64][576]; zero pad ------
__global__ __launch_bounds__(256) void copy_recent_kernel(const u16* __restrict__ kh, const u16* __restrict__ vh,
                                                          u16* __restrict__ kp, u16* __restrict__ vtp) {
  int bid = blockIdx.x;
  if (bid < 2280) {                                  // K rows T=6..575
    int u = bid * 256 + threadIdx.x;                 // = (nh*570 + (T-6))*8 + dq8
    int dq8 = u & 7; int rest = u >> 3; int Tm6 = rest % 570; int nh = rest / 570;
    if (nh >= 128) return;
    uint4 val = {0, 0, 0, 0};
    if (Tm6 < 512) {
      int n = nh >> 4, h = nh & 15;
      val = *(const uint4*)&kh[((size_t)(n * 2048 + 1536 + Tm6)) * 1024 + h * 64 + dq8 * 8];
    }
    *(uint4*)&kp[((size_t)nh * 576 + 6 + Tm6) * 64 + dq8 * 8] = val;
  } else {                                           // V^T cols
    int u = (bid - 2280) * 256 + threadIdx.x;        // = (nh*72 + tch)*64 + d
    int d = u & 63; int rest = u >> 6; int tch = rest % 72; int nh = rest / 72;
    if (nh >= 128) return;
    int n = nh >> 4, h = nh & 15;
#pragma unroll
    for (int ii = 0; ii < 8; ++ii) {
      int T = tch * 8 + ii;
      if (T < 6) continue;                           // written by compression
      u16 v = 0;
      if (T < 518) v = vh[((size_t)(n * 2048 + 1536 + (T - 6))) * 1024 + h * 64 + d];
      vtp[((size_t)nh * 64 + d) * 576 + T] = v;
    }
  }
}

// ---------------- fused attention: per (n,h,64 q-rows); flash over causal chunks of 64 T ----------------
// Logits are bounded: 30*tanh(x) <= 30, so softmax uses FIXED max = 30 -> no online rescale,
// no per-chunk cross-lane reductions. pe = exp(s-30) = exp2(C2 / (exp2(C1*sv)+1)), 6 VALU/logit.
__global__ __launch_bounds__(256) void attn_kernel(const u16* __restrict__ qc, const u16* __restrict__ Kp,
                                                   const u16* __restrict__ VTp, u16* __restrict__ ao) {
  int qt = blockIdx.x, h = blockIdx.y, n = blockIdx.z;
  int tid = threadIdx.x, lane = tid & 63, wv = tid >> 6;
  int l15 = lane & 15, lq = lane >> 4;
  __shared__ u16 KS[4096], VS[4096];                 // 64x64 bf16 chunks, row-XOR-swizzled
  __shared__ u16 PS[4][1024];                        // per-wave P [16][64] bf16 (2KB each)
  int q0 = qt * 64 + wv * 16;
  const u16* qrowp = qc + ((size_t)(n * 2048 + q0 + l15)) * 1024 + h * 64;
  bf16x8 aq0 = *(const bf16x8*)(qrowp + lq * 8);
  bf16x8 aq1 = *(const bf16x8*)(qrowp + 32 + lq * 8);
  const u16* Kph = Kp + (size_t)(n * 16 + h) * 576 * 64;
  const u16* Vph = VTp + (size_t)(n * 16 + h) * 64 * 576;
  f32x4 oa[4] = {};
  float rs[4] = {0.f, 0.f, 0.f, 0.f};
  u16* PSW = &PS[wv][0];
  const float C1 = 0.012022458674074693f;            // 0.125 * (2/30) * log2(e)
  const float C2 = -86.56170245333781f;              // -60 * log2(e)
  int nchunks = min(qt + 1, 9);                      // causal skip: chunk tc covers T < (tc+1)*64
  for (int tc = 0; tc < nchunks; ++tc) {
    int Tbase = tc * 64;
    __syncthreads();
#pragma unroll
    for (int it = 0; it < 2; ++it) {                 // stage K,V chunk (8KB each)
      int slot = it * 256 + tid;                     // 0..511 16B slots
      int row = slot >> 3, qq = slot & 7;
      int sw = (qq ^ (row & 7)) * 8;
      *(uint4*)&KS[row * 64 + sw] = *(const uint4*)&Kph[(size_t)(Tbase + row) * 64 + qq * 8];
      *(uint4*)&VS[row * 64 + sw] = *(const uint4*)&Vph[(size_t)row * 576 + Tbase + qq * 8];
    }
    __syncthreads();
    // S = Q @ K^T for 16 q-rows x 64 T
    f32x4 sv[4];
#pragma unroll
    for (int tt = 0; tt < 4; ++tt) {
      int row = tt * 16 + l15, r7 = row & 7;
      bf16x8 b0 = *(const bf16x8*)&KS[row * 64 + ((lq ^ r7) * 8)];
      bf16x8 b1 = *(const bf16x8*)&KS[row * 64 + (((4 | lq) ^ r7) * 8)];
      f32x4 c = {0.f, 0.f, 0.f, 0.f};
      c = mfma16(aq0, b0, c);
      c = mfma16(aq1, b1, c);
      sv[tt] = c;
    }
    float p[4][4];
    bool needmask = (tc == qt) || (tc == 8);
    if (needmask) {
      int qb = q0 + lq * 4;
#pragma unroll
      for (int tt = 0; tt < 4; ++tt) {
        int T = Tbase + tt * 16 + l15;
        bool tval = (T < 518);
#pragma unroll
        for (int i = 0; i < 4; ++i) {
          float e = __builtin_amdgcn_exp2f(sv[tt][i] * C1);
          float pe = __builtin_amdgcn_exp2f(C2 * __builtin_amdgcn_rcpf(e + 1.f));
          bool ok = tval && (T <= qb + i);
          pe = ok ? pe : 0.f;
          p[tt][i] = pe;
          rs[i] += pe;
        }
      }
    } else {
#pragma unroll
      for (int tt = 0; tt < 4; ++tt)
#pragma unroll
        for (int i = 0; i < 4; ++i) {
          float e = __builtin_amdgcn_exp2f(sv[tt][i] * C1);
          float pe = __builtin_amdgcn_exp2f(C2 * __builtin_amdgcn_rcpf(e + 1.f));
          p[tt][i] = pe;
          rs[i] += pe;
        }
    }
    // P -> LDS (bf16, swizzled), then PV
#pragma unroll
    for (int tt = 0; tt < 4; ++tt)
#pragma unroll
      for (int i = 0; i < 4; ++i) {
        int prow = lq * 4 + i;
        int cb = (tt * 16 + l15) * 2;
        *(u16*)((char*)PSW + prow * 128 + (cb ^ ((prow & 7) << 4))) = f2bf(p[tt][i]);
      }
    bf16x8 pa0, pa1;
    {
      int prow = l15, r7 = (prow & 7) << 4;
      pa0 = *(const bf16x8*)((char*)PSW + prow * 128 + ((lq * 16) ^ r7));
      pa1 = *(const bf16x8*)((char*)PSW + prow * 128 + (((4 | lq) * 16) ^ r7));
    }
#pragma unroll
    for (int ct = 0; ct < 4; ++ct) {
      int row = ct * 16 + l15, r7 = row & 7;
      bf16x8 bv0 = *(const bf16x8*)&VS[row * 64 + ((lq ^ r7) * 8)];
      bf16x8 bv1 = *(const bf16x8*)&VS[row * 64 + (((4 | lq) ^ r7) * 8)];
      oa[ct] = mfma16(pa0, bv0, oa[ct]);
      oa[ct] = mfma16(pa1, bv1, oa[ct]);
    }
  }
  // one final cross-lane sum for the denominators (lanes differing in bits 0-3 share lq)
#pragma unroll
  for (int i = 0; i < 4; ++i)
#pragma unroll
    for (int off = 1; off < 16; off <<= 1) rs[i] += __shfl_xor(rs[i], off, 64);
  u16* aop = ao + ((size_t)(n * 2048)) * 1024 + h * 64;
#pragma unroll
  for (int i = 0; i < 4; ++i) {
    float inv = 1.0f / rs[i];
    int q = q0 + lq * 4 + i;
#pragma unroll
    for (int ct = 0; ct < 4; ++ct) {
      int dv = ct * 16 + l15;
      aop[(size_t)q * 1024 + dv] = f2bf(oa[ct][i] * inv);
    }
  }
}

extern "C" void kernel_launch(void* const* d_in, const int* in_sizes, int n_in,
                              void* d_out, int out_size, void* d_ws, size_t ws_size,
                              hipStream_t stream) {
  const float* q_in = (const float*)d_in[0];
  const float* k_in = (const float*)d_in[1];
  const float* v_in = (const float*)d_in[2];
  const float* ln_w = (const float*)d_in[3];
  const float* ln_b = (const float*)d_in[4];
  const float* Wq = (const float*)d_in[5];
  const float* Wk = (const float*)d_in[6];
  const float* Wv = (const float*)d_in[7];
  const float* Wo = (const float*)d_in[8];
  const float* Wkc = (const float*)d_in[9];
  const float* bkc = (const float*)d_in[10];
  const float* Wvc = (const float*)d_in[11];
  const float* bvc = (const float*)d_in[12];

  char* ws = (char*)d_ws;
  const size_t MB = 1u << 20;
  u16* wqe = (u16*)(ws + 0 * MB);
  u16* wkb = (u16*)(ws + 2 * MB);
  u16* wvb = (u16*)(ws + 4 * MB);
  u16* wob = (u16*)(ws + 6 * MB);
  u16* wkcb = (u16*)(ws + 8 * MB);
  u16* wvcb = (u16*)(ws + 10 * MB);
  float* cost = (float*)(ws + 12 * MB);
  float* sint = (float*)(ws + 12 * MB + 262144);
  u16* xn = (u16*)(ws + 13 * MB);    // 32MB: LN staging; dead after GEMMs -> reused for compress partials
  float* partf = (float*)(ws + 13 * MB);
  u16* qcb = (u16*)(ws + 45 * MB);   // 32MB
  u16* khb = (u16*)(ws + 77 * MB);   // 32MB
  u16* vhb = (u16*)(ws + 109 * MB);  // 32MB
  u16* kp = (u16*)(ws + 141 * MB);   // 9.0MB
  u16* vtp = (u16*)(ws + 141 * MB + 9437184);
  u16* aob = khb;                    // kh dead once attention runs

  // weight prep
  prep_wqe_kernel<<<1024, 256, 0, stream>>>(Wq, wqe);
  cast_w_kernel<<<1024, 256, 0, stream>>>(Wk, wkb);
  cast_w_kernel<<<1024, 256, 0, stream>>>(Wv, wvb);
  cast_w_kernel<<<1024, 256, 0, stream>>>(Wo, wob);
  cast_w_kernel<<<1024, 256, 0, stream>>>(Wkc, wkcb);
  cast_w_kernel<<<1024, 256, 0, stream>>>(Wvc, wvcb);
  rope_table_kernel<<<256, 256, 0, stream>>>(cost, sint);

  dim3 gg(8, 128);
  // q: LN -> GEMM(Wq_eff)
  ln_kernel<<<16384, 256, 0, stream>>>(q_in, ln_w, ln_b, xn);
  gemm_nt<0><<<gg, 256, 0, stream>>>(xn, wqe, qcb, 16384, 1024, 1024);
  // k
  ln_kernel<<<16384, 256, 0, stream>>>(k_in, ln_w, ln_b, xn);
  gemm_nt<0><<<gg, 256, 0, stream>>>(xn, wkb, khb, 16384, 1024, 1024);
  // v
  ln_kernel<<<16384, 256, 0, stream>>>(v_in, ln_w, ln_b, xn);
  gemm_nt<0><<<gg, 256, 0, stream>>>(xn, wvb, vhb, 16384, 1024, 1024);

  rope_kernel<<<16384, 256, 0, stream>>>(qcb, khb, cost, sint);
  compress_partial_kernel<<<dim3(48, 8, 2), 512, 0, stream>>>(khb, vhb, wkcb, wvcb, partf);
  compress_finalize_kernel<<<dim3(192, 2), 256, 0, stream>>>(partf, bkc, bvc, kp, vtp);
  copy_recent_kernel<<<4584, 256, 0, stream>>>(khb, vhb, kp, vtp);
  attn_kernel<<<dim3(32, 16, 8), 256, 0, stream>>>(qcb, kp, vtp, aob);
  gemm_nt<1><<<gg, 256, 0, stream>>>(aob, wob, (float*)d_out, 16384, 1024, 1024);
}

// Round 5
// 445.361 us; speedup vs baseline: 2.0405x; 1.0617x over previous
//
#include <hip/hip_runtime.h>
#include <stdint.h>

#define DEV static __device__ __forceinline__

typedef unsigned short u16;
typedef unsigned int u32;
typedef __attribute__((ext_vector_type(4))) float f32x4;
typedef __attribute__((ext_vector_type(8))) short bf16x8;

DEV float bf2f(u16 u) { u32 x = ((u32)u) << 16; float f; __builtin_memcpy(&f, &x, 4); return f; }
DEV u16 f2bf(float f) { u32 x; __builtin_memcpy(&x, &f, 4); x = x + 0x7fffu + ((x >> 16) & 1u); return (u16)(x >> 16); }
DEV float lo16(u32 p) { u32 x = p << 16; float f; __builtin_memcpy(&f, &x, 4); return f; }
DEV float hi16(u32 p) { u32 x = p & 0xffff0000u; float f; __builtin_memcpy(&f, &x, 4); return f; }
DEV u32 pack2(float a, float b) { return (u32)f2bf(a) | ((u32)f2bf(b) << 16); }

DEV u32 cvtpk(float lo, float hi) {        // one v_cvt_pk_bf16_f32 (no builtin on gfx950)
  u32 r; asm("v_cvt_pk_bf16_f32 %0, %1, %2" : "=v"(r) : "v"(lo), "v"(hi)); return r;
}
DEV bf16x8 pk8(f32x4 a, f32x4 b) {
  union { u32 u[4]; bf16x8 v; } x;
  x.u[0] = cvtpk(a[0], a[1]); x.u[1] = cvtpk(a[2], a[3]);
  x.u[2] = cvtpk(b[0], b[1]); x.u[3] = cvtpk(b[2], b[3]);
  return x.v;
}

DEV f32x4 mfma16(bf16x8 a, bf16x8 b, f32x4 c) {
  return __builtin_amdgcn_mfma_f32_16x16x32_bf16(a, b, c, 0, 0, 0);
}

DEV void gl_lds16(const u16* g, u16* l) {
  __builtin_amdgcn_global_load_lds((const __attribute__((address_space(1))) void*)g,
                                   (__attribute__((address_space(3))) void*)l, 16, 0, 0);
}

// ---------------- weight prep ----------------
// Wq_eff = Wq[g=0] + Wq[g=1] (group-sum folded into projection), cast bf16
__global__ __launch_bounds__(256) void prep_wqe_kernel(const float* __restrict__ Wq, u16* __restrict__ out) {
  int id = blockIdx.x * 256 + threadIdx.x;           // 262144 float4 units
  float4 a = ((const float4*)Wq)[id];
  float4 b = ((const float4*)Wq)[id + 262144];       // +1024*1024 floats
  ushort4 o; o.x = f2bf(a.x + b.x); o.y = f2bf(a.y + b.y); o.z = f2bf(a.z + b.z); o.w = f2bf(a.w + b.w);
  ((ushort4*)out)[id] = o;
}

__global__ __launch_bounds__(256) void cast_w_kernel(const float* __restrict__ src, u16* __restrict__ dst) {
  int id = blockIdx.x * 256 + threadIdx.x;
  float4 a = ((const float4*)src)[id];
  ushort4 o; o.x = f2bf(a.x); o.y = f2bf(a.y); o.z = f2bf(a.z); o.w = f2bf(a.w);
  ((ushort4*)dst)[id] = o;
}

__global__ __launch_bounds__(256) void rope_table_kernel(float* __restrict__ ct, float* __restrict__ st) {
  int id = blockIdx.x * 256 + threadIdx.x;           // 2048*32
  int t = id >> 5, i = id & 31;
  double ang = (double)t * pow(10000.0, -(double)(2 * i) / 64.0);
  ct[id] = (float)cos(ang);
  st[id] = (float)sin(ang);
}

// ---------------- layernorm (one block per 1024-row) ----------------
__global__ __launch_bounds__(256) void ln_kernel(const float* __restrict__ x, const float* __restrict__ w,
                                                 const float* __restrict__ b, u16* __restrict__ out) {
  int row = blockIdx.x, t = threadIdx.x;
  float4 v = ((const float4*)(x + (size_t)row * 1024))[t];
  float s = v.x + v.y + v.z + v.w;
  float s2 = v.x * v.x + v.y * v.y + v.z * v.z + v.w * v.w;
#pragma unroll
  for (int off = 32; off; off >>= 1) { s += __shfl_xor(s, off, 64); s2 += __shfl_xor(s2, off, 64); }
  __shared__ float red[8];
  if ((t & 63) == 0) { red[t >> 6] = s; red[4 + (t >> 6)] = s2; }
  __syncthreads();
  s = red[0] + red[1] + red[2] + red[3];
  s2 = red[4] + red[5] + red[6] + red[7];
  float mu = s * 0.0009765625f;
  float var = s2 * 0.0009765625f - mu * mu;
  float rstd = rsqrtf(var + 1e-5f);
  float4 wv = ((const float4*)w)[t];
  float4 bv = ((const float4*)b)[t];
  ushort4 o;
  o.x = f2bf((v.x - mu) * rstd * wv.x + bv.x);
  o.y = f2bf((v.y - mu) * rstd * wv.y + bv.y);
  o.z = f2bf((v.z - mu) * rstd * wv.z + bv.z);
  o.w = f2bf((v.w - mu) * rstd * wv.w + bv.w);
  *(ushort4*)(out + (size_t)row * 1024 + t * 4) = o;
}

// ---------------- NT GEMM: C[m][n] = sum_k A[m*K+k]*B[n*K+k]  (m97-style 128x128, BK=32) ----------------
// Grid: (x = M/128 row-tiles, y = N/128 col-tiles). x-major => row-band pins to one XCD
// (blockid % 8 constant across its col-tiles) so the A panel is L2-resident, fetched once.
template <int OUTF32>
__global__ __launch_bounds__(256, 2) void gemm_nt(const u16* __restrict__ A, const u16* __restrict__ B,
                                                  void* __restrict__ Cout, int M, int Nd, int K) {
  __shared__ u16 As[4096], Bs[4096];                 // [128 rows][32 k] each, quarter-XOR-swizzled
  int tid = threadIdx.x, lane = tid & 63, wv = tid >> 6;
  int l15 = lane & 15, lq = lane >> 4;
  int bm = blockIdx.x * 128, bn = blockIdx.y * 128;
  int wm = (wv >> 1) * 64, wn = (wv & 1) * 64;
  f32x4 acc[4][4] = {};
  for (int k0 = 0; k0 < K; k0 += 32) {
    __syncthreads();                                 // previous iter's LDS reads done
#pragma unroll
    for (int it = 0; it < 2; ++it) {
      int ia = wv * 2 + it;                          // 8 1KB slabs per tile
      int row = ia * 16 + (lane >> 2);
      int qs = lane & 3;
      int qg = qs ^ (row & 3);                       // pre-swizzled global quarter
      gl_lds16(A + (size_t)(bm + row) * K + k0 + qg * 8, &As[ia * 512]);
      gl_lds16(B + (size_t)(bn + row) * K + k0 + qg * 8, &Bs[ia * 512]);
    }
    __syncthreads();                                 // vmcnt(0) drain before use
    bf16x8 af[4], bfr[4];
#pragma unroll
    for (int mt = 0; mt < 4; ++mt) {
      int r = wm + mt * 16 + l15;
      af[mt] = *(const bf16x8*)&As[r * 32 + ((lq ^ (r & 3)) * 8)];
    }
#pragma unroll
    for (int nt = 0; nt < 4; ++nt) {
      int r = wn + nt * 16 + l15;
      bfr[nt] = *(const bf16x8*)&Bs[r * 32 + ((lq ^ (r & 3)) * 8)];
    }
#pragma unroll
    for (int mt = 0; mt < 4; ++mt)
#pragma unroll
      for (int nt = 0; nt < 4; ++nt)
        acc[mt][nt] = mfma16(af[mt], bfr[nt], acc[mt][nt]);
  }
#pragma unroll
  for (int mt = 0; mt < 4; ++mt)
#pragma unroll
    for (int nt = 0; nt < 4; ++nt)
#pragma unroll
      for (int i = 0; i < 4; ++i) {
        int row = bm + wm + mt * 16 + lq * 4 + i;
        int col = bn + wn + nt * 16 + l15;
        if (OUTF32) ((float*)Cout)[(size_t)row * Nd + col] = acc[mt][nt][i];
        else ((u16*)Cout)[(size_t)row * Nd + col] = f2bf(acc[mt][nt][i]);
      }
}

// ---------------- RoPE in place on qc and kh ([16384][1024] bf16, 64-col heads, interleaved pairs) -------
__global__ __launch_bounds__(256) void rope_kernel(u16* __restrict__ qc, u16* __restrict__ kh,
                                                   const float* __restrict__ ct, const float* __restrict__ st) {
  u32 id = blockIdx.x * 256 + threadIdx.x;
  u16* base = qc;
  if (id >= 2097152u) { base = kh; id -= 2097152u; }
  size_t e0 = (size_t)id * 8;
  int row = (int)(e0 >> 10);
  int col = (int)(e0 & 1023);
  int t = row & 2047;
  int i0 = (col & 63) >> 1;                          // multiple of 4
  float4 c = *(const float4*)(ct + t * 32 + i0);
  float4 s = *(const float4*)(st + t * 32 + i0);
  uint4 u = *(const uint4*)(base + e0);
  float x0 = lo16(u.x), x1 = hi16(u.x), x2 = lo16(u.y), x3 = hi16(u.y);
  float x4 = lo16(u.z), x5 = hi16(u.z), x6 = lo16(u.w), x7 = hi16(u.w);
  uint4 o;
  o.x = pack2(x0 * c.x - x1 * s.x, x1 * c.x + x0 * s.x);
  o.y = pack2(x2 * c.y - x3 * s.y, x3 * c.y + x2 * s.y);
  o.z = pack2(x4 * c.z - x5 * s.z, x5 * c.z + x4 * s.z);
  o.w = pack2(x6 * c.w - x7 * s.w, x7 * c.w + x6 * s.w);
  *(uint4*)(base + e0) = o;
}

// ---------------- segment compression, split-K MFMA (stage 1: partials) ----------------
__global__ __launch_bounds__(512) void compress_partial_kernel(
    const u16* __restrict__ kh, const u16* __restrict__ vh,
    const u16* __restrict__ wkcb, const u16* __restrict__ wvcb,
    float* __restrict__ part) {
  int mt = blockIdx.x, ksl = blockIdx.y, kv = blockIdx.z;
  const u16* src = kv ? vh : kh;
  const u16* W = kv ? wvcb : wkcb;
  int tid = threadIdx.x, lane = tid & 63, wv = tid >> 6;
  int l15 = lane & 15, lq = lane >> 4;
  int r = mt * 16 + l15;                             // row in [0,768)
  int nh = r / 6, s = r % 6;
  int n = nh >> 4, h = nh & 15;
  const u16* arow = src + ((size_t)(n * 2048 + s * 256)) * 1024 + h * 64;
  f32x4 acc[4] = {};
  int kbase = (ksl * 8 + wv) * 256;
#pragma unroll
  for (int ks = 0; ks < 8; ++ks) {
    int k0 = kbase + ks * 32;
    int tau = k0 >> 6, d0 = k0 & 63;
    bf16x8 a = *(const bf16x8*)(arow + (size_t)tau * 1024 + d0 + lq * 8);
#pragma unroll
    for (int nt = 0; nt < 4; ++nt) {
      bf16x8 b = *(const bf16x8*)(W + (size_t)(nt * 16 + l15) * 16384 + k0 + lq * 8);
      acc[nt] = mfma16(a, b, acc[nt]);
    }
  }
  __shared__ float red[8][16][68];                   // 68-stride: 2-way bank alias only (free)
#pragma unroll
  for (int nt = 0; nt < 4; ++nt)
#pragma unroll
    for (int i = 0; i < 4; ++i)
      red[wv][lq * 4 + i][nt * 16 + l15] = acc[nt][i];
  __syncthreads();
  int row = tid >> 5, o0 = (tid & 31) * 2;           // 512 threads -> 16 rows x 32 pairs
  float v0 = 0.f, v1 = 0.f;
#pragma unroll
  for (int w8 = 0; w8 < 8; ++w8) { v0 += red[w8][row][o0]; v1 += red[w8][row][o0 + 1]; }
  size_t base = ((size_t)(kv * 8 + ksl) * 768 + mt * 16 + row) * 64 + o0;
  part[base] = v0;
  part[base + 1] = v1;
}

// stage 2: sum 8 k-slices, bias, elu, scatter to packed K [nh][576][64] / V^T [nh][64][576]
__global__ __launch_bounds__(256) void compress_finalize_kernel(
    const float* __restrict__ part, const float* __restrict__ bkc, const float* __restrict__ bvc,
    u16* __restrict__ kp, u16* __restrict__ vtp) {
  int id = blockIdx.x * 256 + threadIdx.x;           // [0, 49152)
  int kv = blockIdx.y;
  int r = id >> 6, o = id & 63;
  float v = kv ? bvc[o] : bkc[o];
#pragma unroll
  for (int s8 = 0; s8 < 8; ++s8) v += part[((size_t)(kv * 8 + s8) * 768 + r) * 64 + o];
  v = v > 0.f ? v : expm1f(v);                       // elu
  int nh = r / 6, s = r % 6;
  if (kv) vtp[((size_t)nh * 64 + o) * 576 + s] = f2bf(v);
  else    kp[((size_t)nh * 576 + s) * 64 + o] = f2bf(v);
}

// ---------------- copy recent 512 rows into packed K [nh][576][64] and V^T [nh][64][576]; zero pad ------
__global__ __launch_bounds__(256) void copy_recent_kernel(const u16* __restrict__ kh, const u16* __restrict__ vh,
                                                          u16* __restrict__ kp, u16* __restrict__ vtp) {
  int bid = blockIdx.x;
  if (bid < 2280) {                                  // K rows T=6..575
    int u = bid * 256 + threadIdx.x;                 // = (nh*570 + (T-6))*8 + dq8
    int dq8 = u & 7; int rest = u >> 3; int Tm6 = rest % 570; int nh = rest / 570;
    if (nh >= 128) return;
    uint4 val = {0, 0, 0, 0};
    if (Tm6 < 512) {
      int n = nh >> 4, h = nh & 15;
      val = *(const uint4*)&kh[((size_t)(n * 2048 + 1536 + Tm6)) * 1024 + h * 64 + dq8 * 8];
    }
    *(uint4*)&kp[((size_t)nh * 576 + 6 + Tm6) * 64 + dq8 * 8] = val;
  } else {                                           // V^T cols
    int u = (bid - 2280) * 256 + threadIdx.x;        // = (nh*72 + tch)*64 + d
    int d = u & 63; int rest = u >> 6; int tch = rest % 72; int nh = rest / 72;
    if (nh >= 128) return;
    int n = nh >> 4, h = nh & 15;
#pragma unroll
    for (int ii = 0; ii < 8; ++ii) {
      int T = tch * 8 + ii;
      if (T < 6) continue;                           // written by compression
      u16 v = 0;
      if (T < 518) v = vh[((size_t)(n * 2048 + 1536 + (T - 6))) * 1024 + h * 64 + d];
      vtp[((size_t)nh * 64 + d) * 576 + T] = v;
    }
  }
}

// ---------------- fused attention: per (n,h,64 q-rows); flash over causal chunks of 64 T ----------------
// Fixed softmax max = 30 (logits bounded by 30*tanh). P kept in f32 LDS (stride 68: 2-way alias
// only); bf16 conversion done on the READ side where values are register-adjacent (cvt_pk x8).
__global__ __launch_bounds__(256) void attn_kernel(const u16* __restrict__ qc, const u16* __restrict__ Kp,
                                                   const u16* __restrict__ VTp, u16* __restrict__ ao) {
  int qt = blockIdx.x, h = blockIdx.y, n = blockIdx.z;
  int tid = threadIdx.x, lane = tid & 63, wv = tid >> 6;
  int l15 = lane & 15, lq = lane >> 4;
  __shared__ u16 KS[4096], VS[4096];                 // 64x64 bf16 chunks, row-XOR-swizzled
  __shared__ float PS[4][1088];                      // per-wave P [16 rows][68 f32]
  int q0 = qt * 64 + wv * 16;
  const u16* qrowp = qc + ((size_t)(n * 2048 + q0 + l15)) * 1024 + h * 64;
  bf16x8 aq0 = *(const bf16x8*)(qrowp + lq * 8);
  bf16x8 aq1 = *(const bf16x8*)(qrowp + 32 + lq * 8);
  const u16* Kph = Kp + (size_t)(n * 16 + h) * 576 * 64;
  const u16* Vph = VTp + (size_t)(n * 16 + h) * 64 * 576;
  f32x4 oa[4] = {};
  float rs[4] = {0.f, 0.f, 0.f, 0.f};
  float* PSW = &PS[wv][0];
  const float C1 = 0.012022458674074693f;            // 0.125 * (2/30) * log2(e)
  const float C2 = -86.56170245333781f;              // -60 * log2(e)
  int nchunks = min(qt + 1, 9);                      // causal skip: chunk tc covers T < (tc+1)*64
  for (int tc = 0; tc < nchunks; ++tc) {
    int Tbase = tc * 64;
    __syncthreads();
#pragma unroll
    for (int it = 0; it < 2; ++it) {                 // stage K,V chunk (8KB each)
      int slot = it * 256 + tid;                     // 0..511 16B slots
      int row = slot >> 3, qq = slot & 7;
      int sw = (qq ^ (row & 7)) * 8;
      *(uint4*)&KS[row * 64 + sw] = *(const uint4*)&Kph[(size_t)(Tbase + row) * 64 + qq * 8];
      *(uint4*)&VS[row * 64 + sw] = *(const uint4*)&Vph[(size_t)row * 576 + Tbase + qq * 8];
    }
    __syncthreads();
    // S = Q @ K^T for 16 q-rows x 64 T
    f32x4 sv[4];
    __builtin_amdgcn_s_setprio(1);
#pragma unroll
    for (int tt = 0; tt < 4; ++tt) {
      int row = tt * 16 + l15, r7 = row & 7;
      bf16x8 b0 = *(const bf16x8*)&KS[row * 64 + ((lq ^ r7) * 8)];
      bf16x8 b1 = *(const bf16x8*)&KS[row * 64 + (((4 | lq) ^ r7) * 8)];
      f32x4 c = {0.f, 0.f, 0.f, 0.f};
      c = mfma16(aq0, b0, c);
      c = mfma16(aq1, b1, c);
      sv[tt] = c;
    }
    __builtin_amdgcn_s_setprio(0);
    float p[4][4];
    bool needmask = (tc == qt) || (tc == 8);
    if (needmask) {
      int qb = q0 + lq * 4;
#pragma unroll
      for (int tt = 0; tt < 4; ++tt) {
        int T = Tbase + tt * 16 + l15;
        bool tval = (T < 518);
#pragma unroll
        for (int i = 0; i < 4; ++i) {
          float e = __builtin_amdgcn_exp2f(sv[tt][i] * C1);
          float pe = __builtin_amdgcn_exp2f(C2 * __builtin_amdgcn_rcpf(e + 1.f));
          bool ok = tval && (T <= qb + i);
          pe = ok ? pe : 0.f;
          p[tt][i] = pe;
          rs[i] += pe;
        }
      }
    } else {
#pragma unroll
      for (int tt = 0; tt < 4; ++tt)
#pragma unroll
        for (int i = 0; i < 4; ++i) {
          float e = __builtin_amdgcn_exp2f(sv[tt][i] * C1);
          float pe = __builtin_amdgcn_exp2f(C2 * __builtin_amdgcn_rcpf(e + 1.f));
          p[tt][i] = pe;
          rs[i] += pe;
        }
    }
    // P (f32) -> per-wave LDS; no conversion on the write side
#pragma unroll
    for (int tt = 0; tt < 4; ++tt)
#pragma unroll
      for (int i = 0; i < 4; ++i)
        PSW[(lq * 4 + i) * 68 + tt * 16 + l15] = p[tt][i];
    // read back A-fragment rows (register-adjacent) and pack pairs with cvt_pk
    const float* prow = PSW + l15 * 68;
    f32x4 r0a = *(const f32x4*)(prow + lq * 8);
    f32x4 r0b = *(const f32x4*)(prow + lq * 8 + 4);
    f32x4 r1a = *(const f32x4*)(prow + lq * 8 + 32);
    f32x4 r1b = *(const f32x4*)(prow + lq * 8 + 36);
    bf16x8 pa0 = pk8(r0a, r0b);
    bf16x8 pa1 = pk8(r1a, r1b);
    __builtin_amdgcn_s_setprio(1);
#pragma unroll
    for (int ct = 0; ct < 4; ++ct) {
      int row = ct * 16 + l15, r7 = row & 7;
      bf16x8 bv0 = *(const bf16x8*)&VS[row * 64 + ((lq ^ r7) * 8)];
      bf16x8 bv1 = *(const bf16x8*)&VS[row * 64 + (((4 | lq) ^ r7) * 8)];
      oa[ct] = mfma16(pa0, bv0, oa[ct]);
      oa[ct] = mfma16(pa1, bv1, oa[ct]);
    }
    __builtin_amdgcn_s_setprio(0);
  }
  // one final cross-lane sum for the denominators (lanes differing in bits 0-3 share lq)
#pragma unroll
  for (int i = 0; i < 4; ++i)
#pragma unroll
    for (int off = 1; off < 16; off <<= 1) rs[i] += __shfl_xor(rs[i], off, 64);
  u16* aop = ao + ((size_t)(n * 2048)) * 1024 + h * 64;
#pragma unroll
  for (int i = 0; i < 4; ++i) {
    float inv = 1.0f / rs[i];
    int q = q0 + lq * 4 + i;
#pragma unroll
    for (int ct = 0; ct < 4; ++ct) {
      int dv = ct * 16 + l15;
      aop[(size_t)q * 1024 + dv] = f2bf(oa[ct][i] * inv);
    }
  }
}

extern "C" void kernel_launch(void* const* d_in, const int* in_sizes, int n_in,
                              void* d_out, int out_size, void* d_ws, size_t ws_size,
                              hipStream_t stream) {
  const float* q_in = (const float*)d_in[0];
  const float* k_in = (const float*)d_in[1];
  const float* v_in = (const float*)d_in[2];
  const float* ln_w = (const float*)d_in[3];
  const float* ln_b = (const float*)d_in[4];
  const float* Wq = (const float*)d_in[5];
  const float* Wk = (const float*)d_in[6];
  const float* Wv = (const float*)d_in[7];
  const float* Wo = (const float*)d_in[8];
  const float* Wkc = (const float*)d_in[9];
  const float* bkc = (const float*)d_in[10];
  const float* Wvc = (const float*)d_in[11];
  const float* bvc = (const float*)d_in[12];

  char* ws = (char*)d_ws;
  const size_t MB = 1u << 20;
  u16* wqe = (u16*)(ws + 0 * MB);
  u16* wkb = (u16*)(ws + 2 * MB);
  u16* wvb = (u16*)(ws + 4 * MB);
  u16* wob = (u16*)(ws + 6 * MB);
  u16* wkcb = (u16*)(ws + 8 * MB);
  u16* wvcb = (u16*)(ws + 10 * MB);
  float* cost = (float*)(ws + 12 * MB);
  float* sint = (float*)(ws + 12 * MB + 262144);
  u16* xn = (u16*)(ws + 13 * MB);    // 32MB: LN staging; dead after GEMMs -> reused for compress partials
  float* partf = (float*)(ws + 13 * MB);
  u16* qcb = (u16*)(ws + 45 * MB);   // 32MB
  u16* khb = (u16*)(ws + 77 * MB);   // 32MB
  u16* vhb = (u16*)(ws + 109 * MB);  // 32MB
  u16* kp = (u16*)(ws + 141 * MB);   // 9.0MB
  u16* vtp = (u16*)(ws + 141 * MB + 9437184);
  u16* aob = khb;                    // kh dead once attention runs

  // weight prep
  prep_wqe_kernel<<<1024, 256, 0, stream>>>(Wq, wqe);
  cast_w_kernel<<<1024, 256, 0, stream>>>(Wk, wkb);
  cast_w_kernel<<<1024, 256, 0, stream>>>(Wv, wvb);
  cast_w_kernel<<<1024, 256, 0, stream>>>(Wo, wob);
  cast_w_kernel<<<1024, 256, 0, stream>>>(Wkc, wkcb);
  cast_w_kernel<<<1024, 256, 0, stream>>>(Wvc, wvcb);
  rope_table_kernel<<<256, 256, 0, stream>>>(cost, sint);

  dim3 gg(128, 8);                   // x = row tile (pins row-band to one XCD), y = col tile
  // q: LN -> GEMM(Wq_eff)
  ln_kernel<<<16384, 256, 0, stream>>>(q_in, ln_w, ln_b, xn);
  gemm_nt<0><<<gg, 256, 0, stream>>>(xn, wqe, qcb, 16384, 1024, 1024);
  // k
  ln_kernel<<<16384, 256, 0, stream>>>(k_in, ln_w, ln_b, xn);
  gemm_nt<0><<<gg, 256, 0, stream>>>(xn, wkb, khb, 16384, 1024, 1024);
  // v
  ln_kernel<<<16384, 256, 0, stream>>>(v_in, ln_w, ln_b, xn);
  gemm_nt<0><<<gg, 256, 0, stream>>>(xn, wvb, vhb, 16384, 1024, 1024);

  rope_kernel<<<16384, 256, 0, stream>>>(qcb, khb, cost, sint);
  compress_partial_kernel<<<dim3(48, 8, 2), 512, 0, stream>>>(khb, vhb, wkcb, wvcb, partf);
  compress_finalize_kernel<<<dim3(192, 2), 256, 0, stream>>>(partf, bkc, bvc, kp, vtp);
  copy_recent_kernel<<<4584, 256, 0, stream>>>(khb, vhb, kp, vtp);
  attn_kernel<<<dim3(32, 16, 8), 256, 0, stream>>>(qcb, kp, vtp, aob);
  gemm_nt<1><<<gg, 256, 0, stream>>>(aob, wob, (float*)d_out, 16384, 1024, 1024);
}

// Round 6
// 435.127 us; speedup vs baseline: 2.0885x; 1.0235x over previous
//
#include <hip/hip_runtime.h>
#include <stdint.h>

#define DEV static __device__ __forceinline__

typedef unsigned short u16;
typedef unsigned int u32;
typedef __attribute__((ext_vector_type(4))) float f32x4;
typedef __attribute__((ext_vector_type(8))) short bf16x8;

DEV float bf2f(u16 u) { u32 x = ((u32)u) << 16; float f; __builtin_memcpy(&f, &x, 4); return f; }
DEV u16 f2bf(float f) { u32 x; __builtin_memcpy(&x, &f, 4); x = x + 0x7fffu + ((x >> 16) & 1u); return (u16)(x >> 16); }
DEV float lo16(u32 p) { u32 x = p << 16; float f; __builtin_memcpy(&f, &x, 4); return f; }
DEV float hi16(u32 p) { u32 x = p & 0xffff0000u; float f; __builtin_memcpy(&f, &x, 4); return f; }
DEV u32 pack2(float a, float b) { return (u32)f2bf(a) | ((u32)f2bf(b) << 16); }

DEV u32 cvtpk(float lo, float hi) {        // one v_cvt_pk_bf16_f32 (no builtin on gfx950)
  u32 r; asm("v_cvt_pk_bf16_f32 %0, %1, %2" : "=v"(r) : "v"(lo), "v"(hi)); return r;
}
DEV bf16x8 pk8(f32x4 a, f32x4 b) {
  union { u32 u[4]; bf16x8 v; } x;
  x.u[0] = cvtpk(a[0], a[1]); x.u[1] = cvtpk(a[2], a[3]);
  x.u[2] = cvtpk(b[0], b[1]); x.u[3] = cvtpk(b[2], b[3]);
  return x.v;
}

DEV f32x4 mfma16(bf16x8 a, bf16x8 b, f32x4 c) {
  return __builtin_amdgcn_mfma_f32_16x16x32_bf16(a, b, c, 0, 0, 0);
}

DEV void gl_lds16(const u16* g, u16* l) {
  __builtin_amdgcn_global_load_lds((const __attribute__((address_space(1))) void*)g,
                                   (__attribute__((address_space(3))) void*)l, 16, 0, 0);
}

// ---------------- weight prep ----------------
// Wq_eff = Wq[g=0] + Wq[g=1] (group-sum folded into projection), cast bf16
__global__ __launch_bounds__(256) void prep_wqe_kernel(const float* __restrict__ Wq, u16* __restrict__ out) {
  int id = blockIdx.x * 256 + threadIdx.x;           // 262144 float4 units
  float4 a = ((const float4*)Wq)[id];
  float4 b = ((const float4*)Wq)[id + 262144];       // +1024*1024 floats
  ushort4 o; o.x = f2bf(a.x + b.x); o.y = f2bf(a.y + b.y); o.z = f2bf(a.z + b.z); o.w = f2bf(a.w + b.w);
  ((ushort4*)out)[id] = o;
}

__global__ __launch_bounds__(256) void cast_w_kernel(const float* __restrict__ src, u16* __restrict__ dst) {
  int id = blockIdx.x * 256 + threadIdx.x;
  float4 a = ((const float4*)src)[id];
  ushort4 o; o.x = f2bf(a.x); o.y = f2bf(a.y); o.z = f2bf(a.z); o.w = f2bf(a.w);
  ((ushort4*)dst)[id] = o;
}

// cos/sin table as interleaved float2 [t][i0]
__global__ __launch_bounds__(256) void rope_cs_kernel(float* __restrict__ cs) {
  int id = blockIdx.x * 256 + threadIdx.x;           // 2048*32
  int t = id >> 5, i = id & 31;
  double ang = (double)t * pow(10000.0, -(double)(2 * i) / 64.0);
  cs[id * 2] = (float)cos(ang);
  cs[id * 2 + 1] = (float)sin(ang);
}

// ---------------- layernorm (one block per 1024-row) ----------------
__global__ __launch_bounds__(256) void ln_kernel(const float* __restrict__ x, const float* __restrict__ w,
                                                 const float* __restrict__ b, u16* __restrict__ out) {
  int row = blockIdx.x, t = threadIdx.x;
  float4 v = ((const float4*)(x + (size_t)row * 1024))[t];
  float s = v.x + v.y + v.z + v.w;
  float s2 = v.x * v.x + v.y * v.y + v.z * v.z + v.w * v.w;
#pragma unroll
  for (int off = 32; off; off >>= 1) { s += __shfl_xor(s, off, 64); s2 += __shfl_xor(s2, off, 64); }
  __shared__ float red[8];
  if ((t & 63) == 0) { red[t >> 6] = s; red[4 + (t >> 6)] = s2; }
  __syncthreads();
  s = red[0] + red[1] + red[2] + red[3];
  s2 = red[4] + red[5] + red[6] + red[7];
  float mu = s * 0.0009765625f;
  float var = s2 * 0.0009765625f - mu * mu;
  float rstd = rsqrtf(var + 1e-5f);
  float4 wv = ((const float4*)w)[t];
  float4 bv = ((const float4*)b)[t];
  ushort4 o;
  o.x = f2bf((v.x - mu) * rstd * wv.x + bv.x);
  o.y = f2bf((v.y - mu) * rstd * wv.y + bv.y);
  o.z = f2bf((v.z - mu) * rstd * wv.z + bv.z);
  o.w = f2bf((v.w - mu) * rstd * wv.w + bv.w);
  *(ushort4*)(out + (size_t)row * 1024 + t * 4) = o;
}

// ---------------- NT GEMM: C[m][n] = sum_k A[m*K+k]*B[n*K+k]  (m97-style 128x128, BK=32) ----------------
// Grid: (x = M/128 row-tiles, y = N/128 col-tiles). x-major => row-band pins to one XCD.
// MODE: 0 = bf16 out, 1 = f32 out, 2 = bf16 out + fused interleaved RoPE (64-col heads, t=row%2048)
template <int MODE>
__global__ __launch_bounds__(256, 2) void gemm_nt(const u16* __restrict__ A, const u16* __restrict__ B,
                                                  void* __restrict__ Cout, int M, int Nd, int K,
                                                  const float* __restrict__ cs) {
  __shared__ u16 As[4096], Bs[4096];                 // [128 rows][32 k] each, quarter-XOR-swizzled
  int tid = threadIdx.x, lane = tid & 63, wv = tid >> 6;
  int l15 = lane & 15, lq = lane >> 4;
  int bm = blockIdx.x * 128, bn = blockIdx.y * 128;
  int wm = (wv >> 1) * 64, wn = (wv & 1) * 64;
  f32x4 acc[4][4] = {};
  for (int k0 = 0; k0 < K; k0 += 32) {
    __syncthreads();                                 // previous iter's LDS reads done
#pragma unroll
    for (int it = 0; it < 2; ++it) {
      int ia = wv * 2 + it;                          // 8 1KB slabs per tile
      int row = ia * 16 + (lane >> 2);
      int qs = lane & 3;
      int qg = qs ^ (row & 3);                       // pre-swizzled global quarter
      gl_lds16(A + (size_t)(bm + row) * K + k0 + qg * 8, &As[ia * 512]);
      gl_lds16(B + (size_t)(bn + row) * K + k0 + qg * 8, &Bs[ia * 512]);
    }
    __syncthreads();                                 // vmcnt(0) drain before use
    bf16x8 af[4], bfr[4];
#pragma unroll
    for (int mt = 0; mt < 4; ++mt) {
      int r = wm + mt * 16 + l15;
      af[mt] = *(const bf16x8*)&As[r * 32 + ((lq ^ (r & 3)) * 8)];
    }
#pragma unroll
    for (int nt = 0; nt < 4; ++nt) {
      int r = wn + nt * 16 + l15;
      bfr[nt] = *(const bf16x8*)&Bs[r * 32 + ((lq ^ (r & 3)) * 8)];
    }
#pragma unroll
    for (int mt = 0; mt < 4; ++mt)
#pragma unroll
      for (int nt = 0; nt < 4; ++nt)
        acc[mt][nt] = mfma16(af[mt], bfr[nt], acc[mt][nt]);
  }
#pragma unroll
  for (int mt = 0; mt < 4; ++mt)
#pragma unroll
    for (int nt = 0; nt < 4; ++nt)
#pragma unroll
      for (int i = 0; i < 4; ++i) {
        int row = bm + wm + mt * 16 + lq * 4 + i;
        int col = bn + wn + nt * 16 + l15;
        float x = acc[mt][nt][i];
        if (MODE == 1) {
          ((float*)Cout)[(size_t)row * Nd + col] = x;
        } else if (MODE == 0) {
          ((u16*)Cout)[(size_t)row * Nd + col] = f2bf(x);
        } else {
          float xp = __shfl_xor(x, 1, 64);           // partner column (col^1), lane l15^1
          int t = row & 2047;
          int i0 = (col & 63) >> 1;
          float2 csv = *(const float2*)(cs + ((size_t)t * 32 + i0) * 2);
          float r = (col & 1) ? (x * csv.x + xp * csv.y) : (x * csv.x - xp * csv.y);
          ((u16*)Cout)[(size_t)row * Nd + col] = f2bf(r);
        }
      }
}

// ---------------- segment compression, split-K MFMA (stage 1: partials) ----------------
__global__ __launch_bounds__(512) void compress_partial_kernel(
    const u16* __restrict__ kh, const u16* __restrict__ vh,
    const u16* __restrict__ wkcb, const u16* __restrict__ wvcb,
    float* __restrict__ part) {
  int mt = blockIdx.x, ksl = blockIdx.y, kv = blockIdx.z;
  const u16* src = kv ? vh : kh;
  const u16* W = kv ? wvcb : wkcb;
  int tid = threadIdx.x, lane = tid & 63, wv = tid >> 6;
  int l15 = lane & 15, lq = lane >> 4;
  int r = mt * 16 + l15;                             // row in [0,768)
  int nh = r / 6, s = r % 6;
  int n = nh >> 4, h = nh & 15;
  const u16* arow = src + ((size_t)(n * 2048 + s * 256)) * 1024 + h * 64;
  f32x4 acc[4] = {};
  int kbase = (ksl * 8 + wv) * 256;
#pragma unroll
  for (int ks = 0; ks < 8; ++ks) {
    int k0 = kbase + ks * 32;
    int tau = k0 >> 6, d0 = k0 & 63;
    bf16x8 a = *(const bf16x8*)(arow + (size_t)tau * 1024 + d0 + lq * 8);
#pragma unroll
    for (int nt = 0; nt < 4; ++nt) {
      bf16x8 b = *(const bf16x8*)(W + (size_t)(nt * 16 + l15) * 16384 + k0 + lq * 8);
      acc[nt] = mfma16(a, b, acc[nt]);
    }
  }
  __shared__ float red[8][16][68];                   // 68-stride: 2-way bank alias only (free)
#pragma unroll
  for (int nt = 0; nt < 4; ++nt)
#pragma unroll
    for (int i = 0; i < 4; ++i)
      red[wv][lq * 4 + i][nt * 16 + l15] = acc[nt][i];
  __syncthreads();
  int row = tid >> 5, o0 = (tid & 31) * 2;           // 512 threads -> 16 rows x 32 pairs
  float v0 = 0.f, v1 = 0.f;
#pragma unroll
  for (int w8 = 0; w8 < 8; ++w8) { v0 += red[w8][row][o0]; v1 += red[w8][row][o0 + 1]; }
  size_t base = ((size_t)(kv * 8 + ksl) * 768 + mt * 16 + row) * 64 + o0;
  part[base] = v0;
  part[base + 1] = v1;
}

// stage 2: sum 8 k-slices, bias, elu, scatter to packed K [nh][576][64] / V^T [nh][64][576]
__global__ __launch_bounds__(256) void compress_finalize_kernel(
    const float* __restrict__ part, const float* __restrict__ bkc, const float* __restrict__ bvc,
    u16* __restrict__ kp, u16* __restrict__ vtp) {
  int id = blockIdx.x * 256 + threadIdx.x;           // [0, 49152)
  int kv = blockIdx.y;
  int r = id >> 6, o = id & 63;
  float v = kv ? bvc[o] : bkc[o];
#pragma unroll
  for (int s8 = 0; s8 < 8; ++s8) v += part[((size_t)(kv * 8 + s8) * 768 + r) * 64 + o];
  v = v > 0.f ? v : expm1f(v);                       // elu
  int nh = r / 6, s = r % 6;
  if (kv) vtp[((size_t)nh * 64 + o) * 576 + s] = f2bf(v);
  else    kp[((size_t)nh * 576 + s) * 64 + o] = f2bf(v);
}

// ---------------- copy recent 512 rows into packed K [nh][576][64] and V^T [nh][64][576]; zero pad ------
__global__ __launch_bounds__(256) void copy_recent_kernel(const u16* __restrict__ kh, const u16* __restrict__ vh,
                                                          u16* __restrict__ kp, u16* __restrict__ vtp) {
  int bid = blockIdx.x;
  if (bid < 2280) {                                  // K rows T=6..575
    int u = bid * 256 + threadIdx.x;                 // = (nh*570 + (T-6))*8 + dq8
    int dq8 = u & 7; int rest = u >> 3; int Tm6 = rest % 570; int nh = rest / 570;
    if (nh >= 128) return;
    uint4 val = {0, 0, 0, 0};
    if (Tm6 < 512) {
      int n = nh >> 4, h = nh & 15;
      val = *(const uint4*)&kh[((size_t)(n * 2048 + 1536 + Tm6)) * 1024 + h * 64 + dq8 * 8];
    }
    *(uint4*)&kp[((size_t)nh * 576 + 6 + Tm6) * 64 + dq8 * 8] = val;
  } else {                                           // V^T cols
    int u = (bid - 2280) * 256 + threadIdx.x;        // = (nh*72 + tch)*64 + d
    int d = u & 63; int rest = u >> 6; int tch = rest % 72; int nh = rest / 72;
    if (nh >= 128) return;
    int n = nh >> 4, h = nh & 15;
#pragma unroll
    for (int ii = 0; ii < 8; ++ii) {
      int T = tch * 8 + ii;
      if (T < 6) continue;                           // written by compression
      u16 v = 0;
      if (T < 518) v = vh[((size_t)(n * 2048 + 1536 + (T - 6))) * 1024 + h * 64 + d];
      vtp[((size_t)nh * 64 + d) * 576 + T] = v;
    }
  }
}

// ---------------- fused attention: per (n,h,64 q-rows); flash over causal chunks of 64 T ----------------
// Fixed softmax max = 30 (logits bounded by 30*tanh). Async-stage split (T14): chunk tc+1's
// global loads are issued before computing chunk tc, so HBM/L2 latency hides under compute;
// the serial inter-chunk cost is 2 barriers + the ds_writes.
__global__ __launch_bounds__(256) void attn_kernel(const u16* __restrict__ qc, const u16* __restrict__ Kp,
                                                   const u16* __restrict__ VTp, u16* __restrict__ ao) {
  int qt = blockIdx.x, h = blockIdx.y, n = blockIdx.z;
  int tid = threadIdx.x, lane = tid & 63, wv = tid >> 6;
  int l15 = lane & 15, lq = lane >> 4;
  __shared__ u16 KS[4096], VS[4096];                 // 64x64 bf16 chunks, row-XOR-swizzled
  __shared__ float PS[4][1088];                      // per-wave P [16 rows][68 f32]
  int q0 = qt * 64 + wv * 16;
  const u16* qrowp = qc + ((size_t)(n * 2048 + q0 + l15)) * 1024 + h * 64;
  bf16x8 aq0 = *(const bf16x8*)(qrowp + lq * 8);
  bf16x8 aq1 = *(const bf16x8*)(qrowp + 32 + lq * 8);
  const u16* Kph = Kp + (size_t)(n * 16 + h) * 576 * 64;
  const u16* Vph = VTp + (size_t)(n * 16 + h) * 64 * 576;
  f32x4 oa[4] = {};
  float rs[4] = {0.f, 0.f, 0.f, 0.f};
  float* PSW = &PS[wv][0];
  const float C1 = 0.012022458674074693f;            // 0.125 * (2/30) * log2(e)
  const float C2 = -86.56170245333781f;              // -60 * log2(e)
  int nchunks = min(qt + 1, 9);                      // causal skip: chunk tc covers T < (tc+1)*64
  // staging geometry: slot = it*256+tid -> row, 16B column
  int srow0 = tid >> 3, sq0 = tid & 7;               // it=0
  int srow1 = (256 + tid) >> 3, sq1 = tid & 7;       // it=1
  int ksw0 = srow0 * 64 + ((sq0 ^ (srow0 & 7)) * 8);
  int ksw1 = srow1 * 64 + ((sq1 ^ (srow1 & 7)) * 8);
  uint4 kr0, kr1, vr0, vr1;
  {
    kr0 = *(const uint4*)&Kph[(size_t)srow0 * 64 + sq0 * 8];
    kr1 = *(const uint4*)&Kph[(size_t)srow1 * 64 + sq1 * 8];
    vr0 = *(const uint4*)&Vph[(size_t)srow0 * 576 + sq0 * 8];
    vr1 = *(const uint4*)&Vph[(size_t)srow1 * 576 + sq1 * 8];
  }
  for (int tc = 0; tc < nchunks; ++tc) {
    __syncthreads();                                 // prev iter's LDS reads done
    // write already-arrived regs to LDS (compiler inserts the vmcnt wait)
    *(uint4*)&KS[ksw0] = kr0;
    *(uint4*)&KS[ksw1] = kr1;
    *(uint4*)&VS[ksw0] = vr0;
    *(uint4*)&VS[ksw1] = vr1;
    // issue next chunk's loads now; they complete during this chunk's compute
    if (tc + 1 < nchunks) {
      int Tb = (tc + 1) * 64;
      kr0 = *(const uint4*)&Kph[(size_t)(Tb + srow0) * 64 + sq0 * 8];
      kr1 = *(const uint4*)&Kph[(size_t)(Tb + srow1) * 64 + sq1 * 8];
      vr0 = *(const uint4*)&Vph[(size_t)srow0 * 576 + Tb + sq0 * 8];
      vr1 = *(const uint4*)&Vph[(size_t)srow1 * 576 + Tb + sq1 * 8];
    }
    __syncthreads();                                 // LDS writes visible
    // S = Q @ K^T for 16 q-rows x 64 T
    f32x4 sv[4];
    __builtin_amdgcn_s_setprio(1);
#pragma unroll
    for (int tt = 0; tt < 4; ++tt) {
      int row = tt * 16 + l15, r7 = row & 7;
      bf16x8 b0 = *(const bf16x8*)&KS[row * 64 + ((lq ^ r7) * 8)];
      bf16x8 b1 = *(const bf16x8*)&KS[row * 64 + (((4 | lq) ^ r7) * 8)];
      f32x4 c = {0.f, 0.f, 0.f, 0.f};
      c = mfma16(aq0, b0, c);
      c = mfma16(aq1, b1, c);
      sv[tt] = c;
    }
    __builtin_amdgcn_s_setprio(0);
    float p[4][4];
    bool needmask = (tc == qt) || (tc == 8);
    if (needmask) {
      int qb = q0 + lq * 4;
      int Tbase = tc * 64;
#pragma unroll
      for (int tt = 0; tt < 4; ++tt) {
        int T = Tbase + tt * 16 + l15;
        bool tval = (T < 518);
#pragma unroll
        for (int i = 0; i < 4; ++i) {
          float e = __builtin_amdgcn_exp2f(sv[tt][i] * C1);
          float pe = __builtin_amdgcn_exp2f(C2 * __builtin_amdgcn_rcpf(e + 1.f));
          bool ok = tval && (T <= qb + i);
          pe = ok ? pe : 0.f;
          p[tt][i] = pe;
          rs[i] += pe;
        }
      }
    } else {
#pragma unroll
      for (int tt = 0; tt < 4; ++tt)
#pragma unroll
        for (int i = 0; i < 4; ++i) {
          float e = __builtin_amdgcn_exp2f(sv[tt][i] * C1);
          float pe = __builtin_amdgcn_exp2f(C2 * __builtin_amdgcn_rcpf(e + 1.f));
          p[tt][i] = pe;
          rs[i] += pe;
        }
    }
    // P (f32) -> per-wave LDS; bf16 conversion on the read side (register-adjacent pairs)
#pragma unroll
    for (int tt = 0; tt < 4; ++tt)
#pragma unroll
      for (int i = 0; i < 4; ++i)
        PSW[(lq * 4 + i) * 68 + tt * 16 + l15] = p[tt][i];
    const float* prow = PSW + l15 * 68;
    f32x4 r0a = *(const f32x4*)(prow + lq * 8);
    f32x4 r0b = *(const f32x4*)(prow + lq * 8 + 4);
    f32x4 r1a = *(const f32x4*)(prow + lq * 8 + 32);
    f32x4 r1b = *(const f32x4*)(prow + lq * 8 + 36);
    bf16x8 pa0 = pk8(r0a, r0b);
    bf16x8 pa1 = pk8(r1a, r1b);
    __builtin_amdgcn_s_setprio(1);
#pragma unroll
    for (int ct = 0; ct < 4; ++ct) {
      int row = ct * 16 + l15, r7 = row & 7;
      bf16x8 bv0 = *(const bf16x8*)&VS[row * 64 + ((lq ^ r7) * 8)];
      bf16x8 bv1 = *(const bf16x8*)&VS[row * 64 + (((4 | lq) ^ r7) * 8)];
      oa[ct] = mfma16(pa0, bv0, oa[ct]);
      oa[ct] = mfma16(pa1, bv1, oa[ct]);
    }
    __builtin_amdgcn_s_setprio(0);
  }
  // one final cross-lane sum for the denominators
#pragma unroll
  for (int i = 0; i < 4; ++i)
#pragma unroll
    for (int off = 1; off < 16; off <<= 1) rs[i] += __shfl_xor(rs[i], off, 64);
  u16* aop = ao + ((size_t)(n * 2048)) * 1024 + h * 64;
#pragma unroll
  for (int i = 0; i < 4; ++i) {
    float inv = 1.0f / rs[i];
    int q = q0 + lq * 4 + i;
#pragma unroll
    for (int ct = 0; ct < 4; ++ct) {
      int dv = ct * 16 + l15;
      aop[(size_t)q * 1024 + dv] = f2bf(oa[ct][i] * inv);
    }
  }
}

extern "C" void kernel_launch(void* const* d_in, const int* in_sizes, int n_in,
                              void* d_out, int out_size, void* d_ws, size_t ws_size,
                              hipStream_t stream) {
  const float* q_in = (const float*)d_in[0];
  const float* k_in = (const float*)d_in[1];
  const float* v_in = (const float*)d_in[2];
  const float* ln_w = (const float*)d_in[3];
  const float* ln_b = (const float*)d_in[4];
  const float* Wq = (const float*)d_in[5];
  const float* Wk = (const float*)d_in[6];
  const float* Wv = (const float*)d_in[7];
  const float* Wo = (const float*)d_in[8];
  const float* Wkc = (const float*)d_in[9];
  const float* bkc = (const float*)d_in[10];
  const float* Wvc = (const float*)d_in[11];
  const float* bvc = (const float*)d_in[12];

  char* ws = (char*)d_ws;
  const size_t MB = 1u << 20;
  u16* wqe = (u16*)(ws + 0 * MB);
  u16* wkb = (u16*)(ws + 2 * MB);
  u16* wvb = (u16*)(ws + 4 * MB);
  u16* wob = (u16*)(ws + 6 * MB);
  u16* wkcb = (u16*)(ws + 8 * MB);
  u16* wvcb = (u16*)(ws + 10 * MB);
  float* csb = (float*)(ws + 12 * MB);   // 512KB float2 cos/sin table
  u16* xn = (u16*)(ws + 13 * MB);    // 32MB: LN staging; dead after GEMMs -> reused for compress partials
  float* partf = (float*)(ws + 13 * MB);
  u16* qcb = (u16*)(ws + 45 * MB);   // 32MB
  u16* khb = (u16*)(ws + 77 * MB);   // 32MB
  u16* vhb = (u16*)(ws + 109 * MB);  // 32MB
  u16* kp = (u16*)(ws + 141 * MB);   // 9.0MB
  u16* vtp = (u16*)(ws + 141 * MB + 9437184);
  u16* aob = khb;                    // kh dead once attention runs

  // weight prep
  prep_wqe_kernel<<<1024, 256, 0, stream>>>(Wq, wqe);
  cast_w_kernel<<<1024, 256, 0, stream>>>(Wk, wkb);
  cast_w_kernel<<<1024, 256, 0, stream>>>(Wv, wvb);
  cast_w_kernel<<<1024, 256, 0, stream>>>(Wo, wob);
  cast_w_kernel<<<1024, 256, 0, stream>>>(Wkc, wkcb);
  cast_w_kernel<<<1024, 256, 0, stream>>>(Wvc, wvcb);
  rope_cs_kernel<<<256, 256, 0, stream>>>(csb);

  dim3 gg(128, 8);                   // x = row tile (pins row-band to one XCD), y = col tile
  // q: LN -> GEMM(Wq_eff) + fused RoPE
  ln_kernel<<<16384, 256, 0, stream>>>(q_in, ln_w, ln_b, xn);
  gemm_nt<2><<<gg, 256, 0, stream>>>(xn, wqe, qcb, 16384, 1024, 1024, csb);
  // k: LN -> GEMM(Wk) + fused RoPE
  ln_kernel<<<16384, 256, 0, stream>>>(k_in, ln_w, ln_b, xn);
  gemm_nt<2><<<gg, 256, 0, stream>>>(xn, wkb, khb, 16384, 1024, 1024, csb);
  // v
  ln_kernel<<<16384, 256, 0, stream>>>(v_in, ln_w, ln_b, xn);
  gemm_nt<0><<<gg, 256, 0, stream>>>(xn, wvb, vhb, 16384, 1024, 1024, csb);

  compress_partial_kernel<<<dim3(48, 8, 2), 512, 0, stream>>>(khb, vhb, wkcb, wvcb, partf);
  compress_finalize_kernel<<<dim3(192, 2), 256, 0, stream>>>(partf, bkc, bvc, kp, vtp);
  copy_recent_kernel<<<4584, 256, 0, stream>>>(khb, vhb, kp, vtp);
  attn_kernel<<<dim3(32, 16, 8), 256, 0, stream>>>(qcb, kp, vtp, aob);
  gemm_nt<1><<<gg, 256, 0, stream>>>(aob, wob, (float*)d_out, 16384, 1024, 1024, csb);
}